// Round 1
// baseline (3745.376 us; speedup 1.0000x reference)
//
#include <hip/hip_runtime.h>

// Problem constants: B=4, C=256, H=W=64, K=9 (3x3), offsets=18ch.
constexpr int Bsz = 4;
constexpr int Cch = 256;
constexpr int Hh  = 64;
constexpr int Wwd = 64;
constexpr int HWp = Hh * Wwd;            // 4096
constexpr int NPIX = Bsz * HWp;          // 16384

// Workspace layout (floats)
constexpr size_t OFF_PROD = 0;
constexpr size_t OFF_CORR = OFF_PROD + (size_t)NPIX;                 // 16384
constexpr size_t OFF_H1   = OFF_CORR + (size_t)NPIX;                 // 32768
constexpr size_t OFF_H2   = OFF_H1   + (size_t)Bsz*Cch*HWp;          // +4194304
constexpr size_t OFF_OFF3 = OFF_H2   + (size_t)Bsz*Cch*HWp;          // +4194304
constexpr size_t OFF_XT   = OFF_OFF3 + (size_t)Bsz*18*HWp;           // +294912
constexpr size_t OFF_WT   = OFF_XT   + (size_t)Bsz*Cch*HWp;          // +4194304
// total = 13,500,416 floats = 54,001,664 bytes

// ---------------------------------------------------------------------------
// prod[b,y,x] = sum_c x_next[b,c,y,x] * x_ref[b,c,y,x]
__global__ void k_prod(const float* __restrict__ xn, const float* __restrict__ xr,
                       float* __restrict__ prod) {
    int p = blockIdx.x * blockDim.x + threadIdx.x;
    if (p >= NPIX) return;
    int b = p >> 12;
    int yx = p & 4095;
    const float* a = xn + (size_t)b * Cch * HWp + yx;
    const float* c = xr + (size_t)b * Cch * HWp + yx;
    float s = 0.f;
#pragma unroll 8
    for (int ch = 0; ch < Cch; ++ch) s += a[(size_t)ch * HWp] * c[(size_t)ch * HWp];
    prod[p] = s;
}

// corr = leaky_relu(box3x3(prod) / 256)
__global__ void k_corr(const float* __restrict__ prod, float* __restrict__ corr) {
    int p = blockIdx.x * blockDim.x + threadIdx.x;
    if (p >= NPIX) return;
    int b = p >> 12, yx = p & 4095, y = yx >> 6, x = yx & 63;
    float s = 0.f;
    for (int dy = -1; dy <= 1; ++dy) {
        int yy = y + dy;
        if (yy < 0 || yy >= Hh) continue;
        for (int dx = -1; dx <= 1; ++dx) {
            int xx = x + dx;
            if (xx < 0 || xx >= Wwd) continue;
            s += prod[b * HWp + yy * Wwd + xx];
        }
    }
    s *= (1.0f / 256.0f);
    corr[p] = (s > 0.f) ? s : 0.1f * s;
}

// Generic relu(conv3x3 SAME) for NCHW. Block = 16x16 spatial tile for one (b,o).
// grid = (16 tiles, O, B)
template <int CIN>
__global__ void k_conv3x3(const float* __restrict__ in, const float* __restrict__ w,
                          const float* __restrict__ bias, float* __restrict__ out) {
    __shared__ float t[18][19];
    __shared__ float wl[9];
    const int O = gridDim.y;
    const int b = blockIdx.z, o = blockIdx.y;
    const int ty0 = (blockIdx.x >> 2) << 4;
    const int tx0 = (blockIdx.x & 3) << 4;
    const int tx = threadIdx.x, ty = threadIdx.y;
    const int tid = ty * 16 + tx;
    const float* inb = in + (size_t)b * CIN * HWp;

    float acc = bias[o];
    for (int c = 0; c < CIN; ++c) {
        __syncthreads();
        for (int s = tid; s < 324; s += 256) {
            int i = s / 18, j = s - i * 18;
            int yy = ty0 - 1 + i, xx = tx0 - 1 + j;
            float v = 0.f;
            if (yy >= 0 && yy < Hh && xx >= 0 && xx < Wwd)
                v = inb[(size_t)c * HWp + yy * Wwd + xx];
            t[i][j] = v;
        }
        if (tid < 9) wl[tid] = w[((size_t)o * CIN + c) * 9 + tid];
        __syncthreads();
#pragma unroll
        for (int ky = 0; ky < 3; ++ky)
#pragma unroll
            for (int kx = 0; kx < 3; ++kx)
                acc += t[ty + ky][tx + kx] * wl[ky * 3 + kx];
    }
    out[((size_t)b * O + o) * HWp + (ty0 + ty) * Wwd + (tx0 + tx)] = fmaxf(acc, 0.f);
}

// Transpose x_ref NCHW -> NHWC:  xt[b][y][x][c]
__global__ void k_transpose(const float* __restrict__ in, float* __restrict__ out) {
    __shared__ float t[32][33];
    int b = blockIdx.z;
    int c0 = blockIdx.y * 32, p0 = blockIdx.x * 32;
    int tx = threadIdx.x, ty = threadIdx.y;  // 32 x 8
    const size_t bb = (size_t)b * Cch * HWp;
#pragma unroll
    for (int i = 0; i < 32; i += 8)
        t[ty + i][tx] = in[bb + (size_t)(c0 + ty + i) * HWp + p0 + tx];
    __syncthreads();
#pragma unroll
    for (int i = 0; i < 32; i += 8)
        out[bb + (size_t)(p0 + ty + i) * Cch + c0 + tx] = t[tx][ty + i];
}

// Transpose w_dcn (O,C,K) -> wt[(c*9+k)*256 + o]
__global__ void k_wt(const float* __restrict__ w, float* __restrict__ wt) {
    int i = blockIdx.x * 256 + threadIdx.x;
    if (i >= 256 * 256 * 9) return;
    int o = i & 255;
    int ck = i >> 8;
    int c = ck / 9, k = ck - c * 9;
    wt[i] = w[((size_t)o * 256 + c) * 9 + k];
}

// Deformable conv + relu + final average. One block per pixel; 256 threads.
// Phase 1: bilinear-sample 9 taps x 256 channels into LDS (NHWC gathers).
// Phase 2: thread o does 2304-term dot with transposed weights; fuse output.
__global__ void k_dcn(const float* __restrict__ xt, const float* __restrict__ off3,
                      const float* __restrict__ wt, const float* __restrict__ xn,
                      float* __restrict__ out) {
    __shared__ float samp[9 * 256];
    const int p = blockIdx.x;
    const int b = p >> 12, yx = p & 4095, y = yx >> 6, x = yx & 63;
    const int tid = threadIdx.x;
    const float* base = xt + (size_t)b * Cch * HWp;

#pragma unroll
    for (int k = 0; k < 9; ++k) {
        float dy = off3[((size_t)b * 18 + 2 * k) * HWp + yx];
        float dx = off3[((size_t)b * 18 + 2 * k + 1) * HWp + yx];
        float ypos = (float)(y + (k / 3) - 1) + dy;
        float xpos = (float)(x + (k % 3) - 1) + dx;
        float y0f = floorf(ypos), x0f = floorf(xpos);
        float wy = ypos - y0f, wx = xpos - x0f;
        int y0 = (int)y0f, x0 = (int)x0f;
        bool y0v = (y0 >= 0) && (y0 < Hh);
        bool y1v = (y0 + 1 >= 0) && (y0 + 1 < Hh);
        bool x0v = (x0 >= 0) && (x0 < Wwd);
        bool x1v = (x0 + 1 >= 0) && (x0 + 1 < Wwd);
        float v00 = (y0v && x0v) ? base[((size_t)(y0 * Wwd + x0)) * Cch + tid] : 0.f;
        float v01 = (y0v && x1v) ? base[((size_t)(y0 * Wwd + x0 + 1)) * Cch + tid] : 0.f;
        float v10 = (y1v && x0v) ? base[((size_t)((y0 + 1) * Wwd + x0)) * Cch + tid] : 0.f;
        float v11 = (y1v && x1v) ? base[((size_t)((y0 + 1) * Wwd + x0 + 1)) * Cch + tid] : 0.f;
        samp[k * 256 + tid] = v00 * (1.f - wy) * (1.f - wx) + v01 * (1.f - wy) * wx +
                              v10 * wy * (1.f - wx) + v11 * wy * wx;
    }
    __syncthreads();

    const int o = tid;
    float acc = 0.f;
    for (int c = 0; c < 256; ++c) {
#pragma unroll
        for (int k = 0; k < 9; ++k)
            acc += wt[((size_t)(c * 9 + k)) * 256 + o] * samp[k * 256 + c];
    }
    acc = fmaxf(acc, 0.f);
    size_t oi = ((size_t)b * 256 + o) * HWp + yx;
    out[oi] = 0.5f * (xn[oi] + acc);
}

extern "C" void kernel_launch(void* const* d_in, const int* in_sizes, int n_in,
                              void* d_out, int out_size, void* d_ws, size_t ws_size,
                              hipStream_t stream) {
    const float* x_ref  = (const float*)d_in[0];
    const float* x_next = (const float*)d_in[1];
    const float* w1 = (const float*)d_in[2];
    const float* b1 = (const float*)d_in[3];
    const float* w2 = (const float*)d_in[4];
    const float* b2 = (const float*)d_in[5];
    const float* w3 = (const float*)d_in[6];
    const float* b3 = (const float*)d_in[7];
    const float* wd = (const float*)d_in[8];
    float* out = (float*)d_out;
    float* ws = (float*)d_ws;

    float* prod = ws + OFF_PROD;
    float* corr = ws + OFF_CORR;
    float* h1   = ws + OFF_H1;
    float* h2   = ws + OFF_H2;
    float* off3 = ws + OFF_OFF3;
    float* xt   = ws + OFF_XT;
    float* wt   = ws + OFF_WT;

    k_prod<<<NPIX / 256, 256, 0, stream>>>(x_next, x_ref, prod);
    k_corr<<<NPIX / 256, 256, 0, stream>>>(prod, corr);
    k_conv3x3<1><<<dim3(16, 256, Bsz), dim3(16, 16), 0, stream>>>(corr, w1, b1, h1);
    k_conv3x3<256><<<dim3(16, 256, Bsz), dim3(16, 16), 0, stream>>>(h1, w2, b2, h2);
    k_conv3x3<256><<<dim3(16, 18, Bsz), dim3(16, 16), 0, stream>>>(h2, w3, b3, off3);
    k_transpose<<<dim3(HWp / 32, Cch / 32, Bsz), dim3(32, 8), 0, stream>>>(x_ref, xt);
    k_wt<<<(256 * 256 * 9) / 256, 256, 0, stream>>>(wd, wt);
    k_dcn<<<NPIX, 256, 0, stream>>>(xt, off3, wt, x_next, out);
}

// Round 2
// 211.377 us; speedup vs baseline: 17.7190x; 17.7190x over previous
//
#include <hip/hip_runtime.h>

typedef __attribute__((ext_vector_type(8))) short short8v;
typedef __attribute__((ext_vector_type(4))) float f32x4;
typedef __attribute__((ext_vector_type(4))) unsigned int u32x4;

constexpr int Bsz = 4;
constexpr int Hh = 64, Wwd = 64;
constexpr int HWp = Hh * Wwd;            // 4096
constexpr int NPIX = Bsz * HWp;          // 16384
constexpr int HH = 66;                   // halo dim
constexpr int HPIX = HH * HH;            // 4356
constexpr int Kdim = 2304;               // 9*256

// ---- workspace byte offsets (halo bufs first, contiguous, zeroed together)
constexpr size_t B_H1H  = 0;
constexpr size_t HALO_BYTES = (size_t)Bsz * HPIX * 256 * 2;      // 8,921,088
constexpr size_t B_H2H  = B_H1H + HALO_BYTES;
constexpr size_t B_XTH  = B_H2H + HALO_BYTES;
constexpr size_t ZERO_BYTES = 3 * HALO_BYTES;                    // 26,763,264
constexpr size_t B_PROD = ZERO_BYTES;
constexpr size_t B_CORR = B_PROD + (size_t)NPIX * 4;
constexpr size_t B_OFFP = B_CORR + (size_t)NPIX * 4;
constexpr size_t B_WB2  = B_OFFP + (size_t)NPIX * 32 * 4;
constexpr size_t B_WBD  = B_WB2 + (size_t)256 * Kdim * 2;
constexpr size_t B_WB3  = B_WBD + (size_t)256 * Kdim * 2;

static __device__ __forceinline__ unsigned short f2bf(float f) {
    unsigned u = __builtin_bit_cast(unsigned, f);
    u += 0x7FFFu + ((u >> 16) & 1u);
    return (unsigned short)(u >> 16);
}
static __device__ __forceinline__ float bflo(unsigned u) {
    return __builtin_bit_cast(float, u << 16);
}
static __device__ __forceinline__ float bfhi(unsigned u) {
    return __builtin_bit_cast(float, u & 0xFFFF0000u);
}
static __device__ __forceinline__ void gload_lds16(const void* g, void* l) {
    __builtin_amdgcn_global_load_lds((const __attribute__((address_space(1))) unsigned int*)g,
                                     (__attribute__((address_space(3))) unsigned int*)l, 16, 0, 0);
}

// ---------------------------------------------------------------- zero halos
__global__ void k_zero(u32x4* p, int n16) {
    int i = blockIdx.x * blockDim.x + threadIdx.x;
    for (; i < n16; i += gridDim.x * blockDim.x) p[i] = (u32x4){0, 0, 0, 0};
}

// ---------------------------------------------------------------- prod
__global__ void k_prod(const float* __restrict__ xn, const float* __restrict__ xr,
                       float* __restrict__ prod) {
    __shared__ float red[4][64];
    int px0 = blockIdx.x * 64;
    int b = px0 >> 12;
    int pxl = threadIdx.x & 63, cg = threadIdx.x >> 6;
    size_t base = (size_t)b * 256 * HWp + (px0 & 4095) + pxl;
    const float* a = xn + base;
    const float* r = xr + base;
    float s = 0.f;
#pragma unroll 8
    for (int c = cg * 64; c < cg * 64 + 64; ++c)
        s += a[(size_t)c * HWp] * r[(size_t)c * HWp];
    red[cg][pxl] = s;
    __syncthreads();
    if (cg == 0)
        prod[px0 + pxl] = red[0][pxl] + red[1][pxl] + red[2][pxl] + red[3][pxl];
}

// ---------------------------------------------------------------- corr
__global__ void k_corr(const float* __restrict__ prod, float* __restrict__ corr) {
    int p = blockIdx.x * blockDim.x + threadIdx.x;
    if (p >= NPIX) return;
    int b = p >> 12, yx = p & 4095, y = yx >> 6, x = yx & 63;
    float s = 0.f;
    for (int dy = -1; dy <= 1; ++dy) {
        int yy = y + dy;
        if (yy < 0 || yy >= Hh) continue;
        for (int dx = -1; dx <= 1; ++dx) {
            int xx = x + dx;
            if (xx < 0 || xx >= Wwd) continue;
            s += prod[b * HWp + yy * Wwd + xx];
        }
    }
    s *= (1.0f / 256.0f);
    corr[p] = (s > 0.f) ? s : 0.1f * s;
}

// ---------------------------------------------------------------- conv1 (Cin=1) -> h1h NHWC halo bf16
__global__ __launch_bounds__(256) void k_conv1(const float* __restrict__ corr,
                                               const float* __restrict__ w1,
                                               const float* __restrict__ b1,
                                               unsigned short* __restrict__ h1h) {
    __shared__ float pt[3][34];
    int px0 = blockIdx.x * 32;
    int b = px0 >> 12, y = (px0 & 4095) >> 6, x0 = px0 & 63;
    int tid = threadIdx.x;
    if (tid < 102) {
        int i = tid / 34, j = tid - i * 34;
        int yy = y - 1 + i, xx = x0 - 1 + j;
        float v = 0.f;
        if (yy >= 0 && yy < Hh && xx >= 0 && xx < Wwd) v = corr[b * HWp + yy * Wwd + xx];
        pt[i][j] = v;
    }
    float wl[9];
#pragma unroll
    for (int k = 0; k < 9; ++k) wl[k] = w1[tid * 9 + k];
    float bias = b1[tid];
    __syncthreads();
    for (int p = 0; p < 32; ++p) {
        float acc = bias;
#pragma unroll
        for (int ky = 0; ky < 3; ++ky)
#pragma unroll
            for (int kx = 0; kx < 3; ++kx) acc = fmaf(pt[ky][p + kx], wl[ky * 3 + kx], acc);
        acc = fmaxf(acc, 0.f);
        h1h[((size_t)b * HPIX + (y + 1) * HH + (x0 + p + 1)) * 256 + tid] = f2bf(acc);
    }
}

// ---------------------------------------------------------------- x_ref NCHW f32 -> NHWC halo bf16
__global__ void k_xth(const float* __restrict__ in, unsigned short* __restrict__ out) {
    __shared__ float t[32][33];
    int b = blockIdx.z;
    int c0 = blockIdx.y * 32;
    int y = blockIdx.x >> 1, x0 = (blockIdx.x & 1) * 32;
    int tx = threadIdx.x, ty = threadIdx.y;  // 32 x 8
#pragma unroll
    for (int i = 0; i < 32; i += 8)
        t[ty + i][tx] = in[((size_t)b * 256 + c0 + ty + i) * HWp + y * Wwd + x0 + tx];
    __syncthreads();
#pragma unroll
    for (int i = 0; i < 32; i += 8)
        out[((size_t)b * HPIX + (y + 1) * HH + (x0 + ty + i + 1)) * 256 + c0 + tx] =
            f2bf(t[tx][ty + i]);
}

// ---------------------------------------------------------------- weight pack [O][C][9] -> [o][k*256+c] bf16
__global__ void k_pack(const float* __restrict__ w, unsigned short* __restrict__ out, int O_in) {
    int i = blockIdx.x * 256 + threadIdx.x;
    int o = i / Kdim;
    int r = i - o * Kdim;
    int k = r >> 8, c = r & 255;
    float v = (o < O_in) ? w[((size_t)o * 256 + c) * 9 + k] : 0.f;
    out[i] = f2bf(v);
}

// ---------------------------------------------------------------- conv2 GEMM: 64px x 256o, K=2304
__global__ __launch_bounds__(256) void k_conv2g(const unsigned short* __restrict__ h1h,
                                                const unsigned short* __restrict__ wb,
                                                const float* __restrict__ bias,
                                                unsigned short* __restrict__ h2h) {
    __shared__ short A_s[64 * 32];
    __shared__ short B_s[256 * 32];
    const int tid = threadIdx.x;
    const int px0 = blockIdx.x * 64;
    const int b = px0 >> 12;
    const int pxl = tid >> 2, c8 = (tid & 3) * 8;
    const int px = px0 + pxl;
    const int y = (px & 4095) >> 6, x = px & 63;
    const unsigned short* hb = h1h + (size_t)b * HPIX * 256;
    const int wv = tid >> 6, lane = tid & 63;
    const int ow = wv * 64;
    f32x4 acc[4][4] = {};

    for (int tap = 0; tap < 9; ++tap) {
        const int dy = tap / 3 - 1, dx = tap % 3 - 1;
        const unsigned short* asrc = hb + (size_t)((y + 1 + dy) * HH + (x + 1 + dx)) * 256 + c8;
        for (int cc = 0; cc < 8; ++cc) {
            const int K0 = (tap * 8 + cc) * 32;
            gload_lds16(asrc + cc * 32, &A_s[pxl * 32 + c8]);
            const unsigned short* wsrc = wb + K0 + c8;
#pragma unroll
            for (int r = 0; r < 4; ++r) {
                int o = (tid >> 2) + 64 * r;
                gload_lds16(wsrc + (size_t)o * Kdim, &B_s[o * 32 + c8]);
            }
            __syncthreads();
            short8v af[4], bf[4];
#pragma unroll
            for (int m = 0; m < 4; ++m)
                af[m] = *(const short8v*)&A_s[(m * 16 + (lane & 15)) * 32 + (lane >> 4) * 8];
#pragma unroll
            for (int n = 0; n < 4; ++n)
                bf[n] = *(const short8v*)&B_s[(ow + n * 16 + (lane & 15)) * 32 + (lane >> 4) * 8];
#pragma unroll
            for (int m = 0; m < 4; ++m)
#pragma unroll
                for (int n = 0; n < 4; ++n)
                    acc[m][n] = __builtin_amdgcn_mfma_f32_16x16x32_bf16(af[m], bf[n], acc[m][n], 0, 0, 0);
            __syncthreads();
        }
    }
#pragma unroll
    for (int m = 0; m < 4; ++m) {
#pragma unroll
        for (int j = 0; j < 4; ++j) {
            int p2 = px0 + m * 16 + (lane >> 4) * 4 + j;
            int yy = (p2 & 4095) >> 6, xx = p2 & 63;
            unsigned short* dst = h2h + ((size_t)b * HPIX + (yy + 1) * HH + (xx + 1)) * 256;
#pragma unroll
            for (int n = 0; n < 4; ++n) {
                int o = ow + n * 16 + (lane & 15);
                dst[o] = f2bf(fmaxf(acc[m][n][j] + bias[o], 0.f));
            }
        }
    }
}

// ---------------------------------------------------------------- conv3 GEMM: 256px x 32o (18 real)
__global__ __launch_bounds__(256) void k_conv3g(const unsigned short* __restrict__ h2h,
                                                const unsigned short* __restrict__ wb,
                                                const float* __restrict__ bias,
                                                float* __restrict__ offp) {
    __shared__ short A_s[256 * 32];
    __shared__ short B_s[32 * 32];
    const int tid = threadIdx.x;
    const int px0 = blockIdx.x * 256;
    const int b = px0 >> 12;
    const int c8 = (tid & 3) * 8;
    const unsigned short* hb = h2h + (size_t)b * HPIX * 256;
    const int wv = tid >> 6, lane = tid & 63;
    const int pw = wv * 64;
    f32x4 acc[4][2] = {};

    for (int tap = 0; tap < 9; ++tap) {
        const int dy = tap / 3 - 1, dx = tap % 3 - 1;
        const unsigned short* asrc[4];
#pragma unroll
        for (int r = 0; r < 4; ++r) {
            int px = px0 + (tid >> 2) + 64 * r;
            int y = (px & 4095) >> 6, x = px & 63;
            asrc[r] = hb + (size_t)((y + 1 + dy) * HH + (x + 1 + dx)) * 256 + c8;
        }
        for (int cc = 0; cc < 8; ++cc) {
            const int K0 = (tap * 8 + cc) * 32;
#pragma unroll
            for (int r = 0; r < 4; ++r)
                gload_lds16(asrc[r] + cc * 32, &A_s[((tid >> 2) + 64 * r) * 32 + c8]);
            if (tid < 128)
                gload_lds16(wb + (size_t)(tid >> 2) * Kdim + K0 + c8, &B_s[(tid >> 2) * 32 + c8]);
            __syncthreads();
            short8v af[4], bf[2];
#pragma unroll
            for (int m = 0; m < 4; ++m)
                af[m] = *(const short8v*)&A_s[(pw + m * 16 + (lane & 15)) * 32 + (lane >> 4) * 8];
#pragma unroll
            for (int n = 0; n < 2; ++n)
                bf[n] = *(const short8v*)&B_s[(n * 16 + (lane & 15)) * 32 + (lane >> 4) * 8];
#pragma unroll
            for (int m = 0; m < 4; ++m)
#pragma unroll
                for (int n = 0; n < 2; ++n)
                    acc[m][n] = __builtin_amdgcn_mfma_f32_16x16x32_bf16(af[m], bf[n], acc[m][n], 0, 0, 0);
            __syncthreads();
        }
    }
#pragma unroll
    for (int m = 0; m < 4; ++m)
#pragma unroll
        for (int j = 0; j < 4; ++j) {
            int p2 = px0 + pw + m * 16 + (lane >> 4) * 4 + j;
#pragma unroll
            for (int n = 0; n < 2; ++n) {
                int o = n * 16 + (lane & 15);
                float bv = (o < 18) ? bias[o] : 0.f;
                offp[(size_t)p2 * 32 + o] = fmaxf(acc[m][n][j] + bv, 0.f);
            }
        }
}

// ---------------------------------------------------------------- dcn GEMM: fused bilinear sampling
__global__ __launch_bounds__(256) void k_dcng(const unsigned short* __restrict__ xth,
                                              const float* __restrict__ offp,
                                              const unsigned short* __restrict__ wbd,
                                              const float* __restrict__ xn,
                                              float* __restrict__ out) {
    __shared__ short A_s[64 * 32];    // samples [px][k]
    __shared__ short B_s[256 * 32];   // weights [o][k]
    const int tid = threadIdx.x;
    const int px0 = blockIdx.x * 64;
    const int b = px0 >> 12;
    const int pxl = tid >> 2, c8 = (tid & 3) * 8;
    const int px = px0 + pxl;
    const int y = (px & 4095) >> 6, x = px & 63;
    const unsigned short* xb = xth + (size_t)b * HPIX * 256;
    const int wv = tid >> 6, lane = tid & 63;
    const int ow = wv * 64;
    f32x4 acc[4][4] = {};

    for (int tap = 0; tap < 9; ++tap) {
        float dyo = offp[(size_t)px * 32 + 2 * tap];
        float dxo = offp[(size_t)px * 32 + 2 * tap + 1];
        float ypos = (float)(y + tap / 3 - 1) + dyo;
        float xpos = (float)(x + tap % 3 - 1) + dxo;
        float y0f = floorf(ypos), x0f = floorf(xpos);
        float wy = ypos - y0f, wx = xpos - x0f;
        int y0 = (int)y0f, x0 = (int)x0f;
        bool y0v = (y0 >= 0) && (y0 < Hh), y1v = (y0 + 1 >= 0) && (y0 + 1 < Hh);
        bool x0v = (x0 >= 0) && (x0 < Wwd), x1v = (x0 + 1 >= 0) && (x0 + 1 < Wwd);
        int hy0 = min(max(y0, -1), 64) + 1, hy1 = min(max(y0 + 1, -1), 64) + 1;
        int hx0 = min(max(x0, -1), 64) + 1, hx1 = min(max(x0 + 1, -1), 64) + 1;
        float w00 = (1.f - wy) * (1.f - wx) * (float)(y0v && x0v);
        float w01 = (1.f - wy) * wx * (float)(y0v && x1v);
        float w10 = wy * (1.f - wx) * (float)(y1v && x0v);
        float w11 = wy * wx * (float)(y1v && x1v);
        const unsigned short* p00 = xb + (size_t)(hy0 * HH + hx0) * 256 + c8;
        const unsigned short* p01 = xb + (size_t)(hy0 * HH + hx1) * 256 + c8;
        const unsigned short* p10 = xb + (size_t)(hy1 * HH + hx0) * 256 + c8;
        const unsigned short* p11 = xb + (size_t)(hy1 * HH + hx1) * 256 + c8;

        for (int cc = 0; cc < 8; ++cc) {
            const int K0 = (tap * 8 + cc) * 32;
            const int co = cc * 32;
            u32x4 u00 = *(const u32x4*)(p00 + co);
            u32x4 u01 = *(const u32x4*)(p01 + co);
            u32x4 u10 = *(const u32x4*)(p10 + co);
            u32x4 u11 = *(const u32x4*)(p11 + co);
            const unsigned short* wsrc = wbd + K0 + c8;
#pragma unroll
            for (int r = 0; r < 4; ++r) {
                int o = (tid >> 2) + 64 * r;
                gload_lds16(wsrc + (size_t)o * Kdim, &B_s[o * 32 + c8]);
            }
            u32x4 res;
#pragma unroll
            for (int q = 0; q < 4; ++q) {
                float lo = w00 * bflo(u00[q]) + w01 * bflo(u01[q]) + w10 * bflo(u10[q]) + w11 * bflo(u11[q]);
                float hi = w00 * bfhi(u00[q]) + w01 * bfhi(u01[q]) + w10 * bfhi(u10[q]) + w11 * bfhi(u11[q]);
                res[q] = (unsigned)f2bf(lo) | ((unsigned)f2bf(hi) << 16);
            }
            *(u32x4*)&A_s[pxl * 32 + c8] = res;
            __syncthreads();
            short8v wf[4], sf[4];
#pragma unroll
            for (int m = 0; m < 4; ++m)
                wf[m] = *(const short8v*)&B_s[(ow + m * 16 + (lane & 15)) * 32 + (lane >> 4) * 8];
#pragma unroll
            for (int n = 0; n < 4; ++n)
                sf[n] = *(const short8v*)&A_s[(n * 16 + (lane & 15)) * 32 + (lane >> 4) * 8];
#pragma unroll
            for (int m = 0; m < 4; ++m)
#pragma unroll
                for (int n = 0; n < 4; ++n)
                    acc[m][n] = __builtin_amdgcn_mfma_f32_16x16x32_bf16(wf[m], sf[n], acc[m][n], 0, 0, 0);
            __syncthreads();
        }
    }
    // C rows = o, cols = px -> NCHW coalesced (16 consecutive px per quarter-wave)
#pragma unroll
    for (int m = 0; m < 4; ++m) {
        int o = ow + m * 16 + (lane >> 4) * 4;
#pragma unroll
        for (int j = 0; j < 4; ++j) {
            size_t rowbase = ((size_t)b * 256 + o + j) * HWp;
#pragma unroll
            for (int n = 0; n < 4; ++n) {
                int p2 = px0 + n * 16 + (lane & 15);
                size_t idx = rowbase + (p2 & 4095);
                out[idx] = 0.5f * (xn[idx] + fmaxf(acc[m][n][j], 0.f));
            }
        }
    }
}

extern "C" void kernel_launch(void* const* d_in, const int* in_sizes, int n_in,
                              void* d_out, int out_size, void* d_ws, size_t ws_size,
                              hipStream_t stream) {
    const float* x_ref  = (const float*)d_in[0];
    const float* x_next = (const float*)d_in[1];
    const float* w1 = (const float*)d_in[2];
    const float* b1 = (const float*)d_in[3];
    const float* w2 = (const float*)d_in[4];
    const float* b2 = (const float*)d_in[5];
    const float* w3 = (const float*)d_in[6];
    const float* b3 = (const float*)d_in[7];
    const float* wd = (const float*)d_in[8];
    float* out = (float*)d_out;
    char* ws = (char*)d_ws;

    unsigned short* h1h = (unsigned short*)(ws + B_H1H);
    unsigned short* h2h = (unsigned short*)(ws + B_H2H);
    unsigned short* xth = (unsigned short*)(ws + B_XTH);
    float* prod = (float*)(ws + B_PROD);
    float* corr = (float*)(ws + B_CORR);
    float* offp = (float*)(ws + B_OFFP);
    unsigned short* wb2 = (unsigned short*)(ws + B_WB2);
    unsigned short* wbd = (unsigned short*)(ws + B_WBD);
    unsigned short* wb3 = (unsigned short*)(ws + B_WB3);

    k_zero<<<1024, 256, 0, stream>>>((u32x4*)ws, (int)(ZERO_BYTES / 16));
    k_prod<<<NPIX / 64, 256, 0, stream>>>(x_next, x_ref, prod);
    k_corr<<<NPIX / 256, 256, 0, stream>>>(prod, corr);
    k_conv1<<<NPIX / 32, 256, 0, stream>>>(corr, w1, b1, h1h);
    k_xth<<<dim3(128, 8, Bsz), dim3(32, 8), 0, stream>>>(x_ref, xth);
    k_pack<<<(256 * Kdim) / 256, 256, 0, stream>>>(w2, wb2, 256);
    k_pack<<<(256 * Kdim) / 256, 256, 0, stream>>>(wd, wbd, 256);
    k_pack<<<(32 * Kdim) / 256, 256, 0, stream>>>(w3, wb3, 18);
    k_conv2g<<<NPIX / 64, 256, 0, stream>>>(h1h, wb2, b2, h2h);
    k_conv3g<<<NPIX / 256, 256, 0, stream>>>(h2h, wb3, b3, offp);
    k_dcng<<<NPIX / 64, 256, 0, stream>>>(xth, offp, wbd, x_next, out);
}

// Round 3
// 156.703 us; speedup vs baseline: 23.9011x; 1.3489x over previous
//
#include <hip/hip_runtime.h>

typedef __attribute__((ext_vector_type(8))) short short8v;
typedef __attribute__((ext_vector_type(4))) float f32x4;
typedef __attribute__((ext_vector_type(4))) unsigned int u32x4;

constexpr int Bsz = 4;
constexpr int Hh = 64, Wwd = 64;
constexpr int HWp = Hh * Wwd;            // 4096
constexpr int NPIX = Bsz * HWp;          // 16384
constexpr int HH = 66;                   // halo dim
constexpr int HPIX = HH * HH;            // 4356
constexpr int Kdim = 2304;               // 9*256
constexpr int NSTEP = 36;                // Kdim / 64

// ---- workspace byte offsets
constexpr size_t B_H1H  = 0;
constexpr size_t HALO_BYTES = (size_t)Bsz * HPIX * 256 * 2;      // 8,921,088
constexpr size_t B_H2H  = B_H1H + HALO_BYTES;
constexpr size_t B_XTH  = B_H2H + HALO_BYTES;
constexpr size_t B_PROD = B_XTH + HALO_BYTES;
constexpr size_t B_CORR = B_PROD + (size_t)NPIX * 4;
constexpr size_t B_OFFP = B_CORR + (size_t)NPIX * 4;
constexpr size_t B_WB2  = B_OFFP + (size_t)NPIX * 32 * 4;
constexpr size_t B_WBD  = B_WB2 + (size_t)256 * Kdim * 2;
constexpr size_t B_WB3  = B_WBD + (size_t)256 * Kdim * 2;

static __device__ __forceinline__ unsigned short f2bf(float f) {
    unsigned u = __builtin_bit_cast(unsigned, f);
    u += 0x7FFFu + ((u >> 16) & 1u);
    return (unsigned short)(u >> 16);
}
static __device__ __forceinline__ float bflo(unsigned u) {
    return __builtin_bit_cast(float, u << 16);
}
static __device__ __forceinline__ float bfhi(unsigned u) {
    return __builtin_bit_cast(float, u & 0xFFFF0000u);
}
static __device__ __forceinline__ void gload_lds16(const void* g, void* l) {
    __builtin_amdgcn_global_load_lds((const __attribute__((address_space(1))) unsigned int*)g,
                                     (__attribute__((address_space(3))) unsigned int*)l, 16, 0, 0);
}
// T2 swizzle: 16B-unit u -> short offset of that unit's data within its 64-k row
static __device__ __forceinline__ int swz(int u) {
    return (((u & 7) ^ ((u >> 3) & 7)) << 3);
}

// ---------------------------------------------------------------- zero halo rings only
__global__ void k_zero_ring(unsigned short* h1h, unsigned short* h2h, unsigned short* xth) {
    int blk = blockIdx.x;             // 12 images * 260 ring px
    int img = blk / 260;
    int rp = blk - img * 260;
    int buf = img >> 2, b = img & 3;
    int y, x;
    if (rp < 66) { y = 0; x = rp; }
    else if (rp < 132) { y = 65; x = rp - 66; }
    else { int s2 = rp - 132; y = 1 + (s2 >> 1); x = (s2 & 1) * 65; }
    unsigned short* base = (buf == 0) ? h1h : (buf == 1) ? h2h : xth;
    unsigned* p = (unsigned*)(base + ((size_t)b * HPIX + y * HH + x) * 256);
    p[threadIdx.x] = 0;               // 128 threads x 4B = 512B (256 ch bf16)
}

// ---------------------------------------------------------------- prod
__global__ void k_prod(const float* __restrict__ xn, const float* __restrict__ xr,
                       float* __restrict__ prod) {
    __shared__ float red[4][64];
    int px0 = blockIdx.x * 64;
    int b = px0 >> 12;
    int pxl = threadIdx.x & 63, cg = threadIdx.x >> 6;
    size_t base = (size_t)b * 256 * HWp + (px0 & 4095) + pxl;
    const float* a = xn + base;
    const float* r = xr + base;
    float s = 0.f;
#pragma unroll 8
    for (int c = cg * 64; c < cg * 64 + 64; ++c)
        s += a[(size_t)c * HWp] * r[(size_t)c * HWp];
    red[cg][pxl] = s;
    __syncthreads();
    if (cg == 0)
        prod[px0 + pxl] = red[0][pxl] + red[1][pxl] + red[2][pxl] + red[3][pxl];
}

// ---------------------------------------------------------------- corr
__global__ void k_corr(const float* __restrict__ prod, float* __restrict__ corr) {
    int p = blockIdx.x * blockDim.x + threadIdx.x;
    if (p >= NPIX) return;
    int b = p >> 12, yx = p & 4095, y = yx >> 6, x = yx & 63;
    float s = 0.f;
    for (int dy = -1; dy <= 1; ++dy) {
        int yy = y + dy;
        if (yy < 0 || yy >= Hh) continue;
        for (int dx = -1; dx <= 1; ++dx) {
            int xx = x + dx;
            if (xx < 0 || xx >= Wwd) continue;
            s += prod[b * HWp + yy * Wwd + xx];
        }
    }
    s *= (1.0f / 256.0f);
    corr[p] = (s > 0.f) ? s : 0.1f * s;
}

// ---------------------------------------------------------------- conv1 (Cin=1) -> h1h NHWC halo bf16
__global__ __launch_bounds__(256) void k_conv1(const float* __restrict__ corr,
                                               const float* __restrict__ w1,
                                               const float* __restrict__ b1,
                                               unsigned short* __restrict__ h1h) {
    __shared__ float pt[3][34];
    int px0 = blockIdx.x * 32;
    int b = px0 >> 12, y = (px0 & 4095) >> 6, x0 = px0 & 63;
    int tid = threadIdx.x;
    if (tid < 102) {
        int i = tid / 34, j = tid - i * 34;
        int yy = y - 1 + i, xx = x0 - 1 + j;
        float v = 0.f;
        if (yy >= 0 && yy < Hh && xx >= 0 && xx < Wwd) v = corr[b * HWp + yy * Wwd + xx];
        pt[i][j] = v;
    }
    float wl[9];
#pragma unroll
    for (int k = 0; k < 9; ++k) wl[k] = w1[tid * 9 + k];
    float bias = b1[tid];
    __syncthreads();
    for (int p = 0; p < 32; ++p) {
        float acc = bias;
#pragma unroll
        for (int ky = 0; ky < 3; ++ky)
#pragma unroll
            for (int kx = 0; kx < 3; ++kx) acc = fmaf(pt[ky][p + kx], wl[ky * 3 + kx], acc);
        acc = fmaxf(acc, 0.f);
        h1h[((size_t)b * HPIX + (y + 1) * HH + (x0 + p + 1)) * 256 + tid] = f2bf(acc);
    }
}

// ---------------------------------------------------------------- x_ref NCHW f32 -> NHWC halo bf16
__global__ void k_xth(const float* __restrict__ in, unsigned short* __restrict__ out) {
    __shared__ float t[32][33];
    int b = blockIdx.z;
    int c0 = blockIdx.y * 32;
    int y = blockIdx.x >> 1, x0 = (blockIdx.x & 1) * 32;
    int tx = threadIdx.x, ty = threadIdx.y;  // 32 x 8
#pragma unroll
    for (int i = 0; i < 32; i += 8)
        t[ty + i][tx] = in[((size_t)b * 256 + c0 + ty + i) * HWp + y * Wwd + x0 + tx];
    __syncthreads();
#pragma unroll
    for (int i = 0; i < 32; i += 8)
        out[((size_t)b * HPIX + (y + 1) * HH + (x0 + ty + i + 1)) * 256 + c0 + tx] =
            f2bf(t[tx][ty + i]);
}

// ---------------------------------------------------------------- weight pack [O][C][9] -> [o][tap*256+c] bf16
__global__ void k_pack(const float* __restrict__ w, unsigned short* __restrict__ out, int O_in) {
    int i = blockIdx.x * 256 + threadIdx.x;
    int o = i / Kdim;
    int r = i - o * Kdim;
    int k = r >> 8, c = r & 255;
    float v = (o < O_in) ? w[((size_t)o * 256 + c) * 9 + k] : 0.f;
    out[i] = f2bf(v);
}

// ---------------------------------------------------------------- conv2 GEMM: 64px x 128o tile, BK=64, dbuf
__global__ __launch_bounds__(256) void k_conv2g(const unsigned short* __restrict__ h1h,
                                                const unsigned short* __restrict__ wb,
                                                const float* __restrict__ bias,
                                                unsigned short* __restrict__ h2h) {
    __shared__ short A_s[2][64 * 64];
    __shared__ short B_s[2][128 * 64];
    const int tid = threadIdx.x;
    const int px0 = blockIdx.x * 64;
    const int oblk = blockIdx.y;
    const int b = px0 >> 12;
    const unsigned short* hb = h1h + (size_t)b * HPIX * 256;

    const unsigned short* abase[2];
#pragma unroll
    for (int i = 0; i < 2; ++i) {
        int u = i * 256 + tid;
        int pxl = u >> 3;
        int pxg = px0 + pxl;
        int y = (pxg & 4095) >> 6, x = pxg & 63;
        abase[i] = hb + (size_t)((y + 1) * HH + (x + 1)) * 256 + swz(u);
    }
    const unsigned short* bbase[4];
#pragma unroll
    for (int i = 0; i < 4; ++i) {
        int u = i * 256 + tid;
        int ol = u >> 3;
        bbase[i] = wb + (size_t)(oblk * 128 + ol) * Kdim + swz(u);
    }

    const int lane = tid & 63, wv = tid >> 6;
    const int wm = wv >> 1, wn = wv & 1;     // wave tile: 32px x 64o
    f32x4 acc[2][4] = {};

    auto STAGE = [&](int s, int buf) {
        int tap = s >> 2, chunk = s & 3;
        int delta = ((tap / 3 - 1) * HH + (tap % 3 - 1)) * 256 + chunk * 64;
        short* Ab = &A_s[buf][0];
        short* Bb = &B_s[buf][0];
#pragma unroll
        for (int i = 0; i < 2; ++i) gload_lds16(abase[i] + delta, Ab + (i * 256 + tid) * 8);
#pragma unroll
        for (int i = 0; i < 4; ++i) gload_lds16(bbase[i] + s * 64, Bb + (i * 256 + tid) * 8);
    };

    STAGE(0, 0);
    __syncthreads();
    for (int s = 0; s < NSTEP; ++s) {
        int cur = s & 1;
        if (s + 1 < NSTEP) STAGE(s + 1, cur ^ 1);
        const short* Ab = &A_s[cur][0];
        const short* Bb = &B_s[cur][0];
        short8v af[2][2], bf[4][2];
#pragma unroll
        for (int mi = 0; mi < 2; ++mi) {
            int row = wm * 32 + mi * 16 + (lane & 15);
#pragma unroll
            for (int kf = 0; kf < 2; ++kf) {
                int c8 = kf * 4 + (lane >> 4);
                af[mi][kf] = *(const short8v*)&Ab[row * 64 + ((c8 ^ (row & 7)) << 3)];
            }
        }
#pragma unroll
        for (int ni = 0; ni < 4; ++ni) {
            int row = wn * 64 + ni * 16 + (lane & 15);
#pragma unroll
            for (int kf = 0; kf < 2; ++kf) {
                int c8 = kf * 4 + (lane >> 4);
                bf[ni][kf] = *(const short8v*)&Bb[row * 64 + ((c8 ^ (row & 7)) << 3)];
            }
        }
#pragma unroll
        for (int kf = 0; kf < 2; ++kf)
#pragma unroll
            for (int mi = 0; mi < 2; ++mi)
#pragma unroll
                for (int ni = 0; ni < 4; ++ni)
                    acc[mi][ni] = __builtin_amdgcn_mfma_f32_16x16x32_bf16(af[mi][kf], bf[ni][kf],
                                                                          acc[mi][ni], 0, 0, 0);
        __syncthreads();
    }
#pragma unroll
    for (int mi = 0; mi < 2; ++mi) {
#pragma unroll
        for (int j = 0; j < 4; ++j) {
            int px = px0 + wm * 32 + mi * 16 + (lane >> 4) * 4 + j;
            int y = (px & 4095) >> 6, x = px & 63;
            unsigned short* dst = h2h + ((size_t)b * HPIX + (y + 1) * HH + (x + 1)) * 256;
#pragma unroll
            for (int ni = 0; ni < 4; ++ni) {
                int o = oblk * 128 + wn * 64 + ni * 16 + (lane & 15);
                dst[o] = f2bf(fmaxf(acc[mi][ni][j] + bias[o], 0.f));
            }
        }
    }
}

// ---------------------------------------------------------------- conv3 GEMM: 64px x 32o, BK=64, dbuf
__global__ __launch_bounds__(256) void k_conv3g(const unsigned short* __restrict__ h2h,
                                                const unsigned short* __restrict__ wb,
                                                const float* __restrict__ bias,
                                                float* __restrict__ offp) {
    __shared__ short A_s[2][64 * 64];
    __shared__ short B_s[2][32 * 64];
    const int tid = threadIdx.x;
    const int px0 = blockIdx.x * 64;
    const int b = px0 >> 12;
    const unsigned short* hb = h2h + (size_t)b * HPIX * 256;

    const unsigned short* abase[2];
#pragma unroll
    for (int i = 0; i < 2; ++i) {
        int u = i * 256 + tid;
        int pxl = u >> 3;
        int pxg = px0 + pxl;
        int y = (pxg & 4095) >> 6, x = pxg & 63;
        abase[i] = hb + (size_t)((y + 1) * HH + (x + 1)) * 256 + swz(u);
    }
    const unsigned short* bbase = wb + (size_t)(tid >> 3) * Kdim + swz(tid);

    const int lane = tid & 63, wv = tid >> 6;   // wave tile: 16px x 32o
    f32x4 acc[2] = {};

    auto STAGE = [&](int s, int buf) {
        int tap = s >> 2, chunk = s & 3;
        int delta = ((tap / 3 - 1) * HH + (tap % 3 - 1)) * 256 + chunk * 64;
        short* Ab = &A_s[buf][0];
#pragma unroll
        for (int i = 0; i < 2; ++i) gload_lds16(abase[i] + delta, Ab + (i * 256 + tid) * 8);
        gload_lds16(bbase + s * 64, &B_s[buf][tid * 8]);
    };

    STAGE(0, 0);
    __syncthreads();
    for (int s = 0; s < NSTEP; ++s) {
        int cur = s & 1;
        if (s + 1 < NSTEP) STAGE(s + 1, cur ^ 1);
        const short* Ab = &A_s[cur][0];
        const short* Bb = &B_s[cur][0];
        short8v af[2], bf[2][2];
#pragma unroll
        for (int kf = 0; kf < 2; ++kf) {
            int row = wv * 16 + (lane & 15);
            int c8 = kf * 4 + (lane >> 4);
            af[kf] = *(const short8v*)&Ab[row * 64 + ((c8 ^ (row & 7)) << 3)];
        }
#pragma unroll
        for (int ni = 0; ni < 2; ++ni) {
            int row = ni * 16 + (lane & 15);
#pragma unroll
            for (int kf = 0; kf < 2; ++kf) {
                int c8 = kf * 4 + (lane >> 4);
                bf[ni][kf] = *(const short8v*)&Bb[row * 64 + ((c8 ^ (row & 7)) << 3)];
            }
        }
#pragma unroll
        for (int kf = 0; kf < 2; ++kf)
#pragma unroll
            for (int ni = 0; ni < 2; ++ni)
                acc[ni] = __builtin_amdgcn_mfma_f32_16x16x32_bf16(af[kf], bf[ni][kf], acc[ni], 0, 0, 0);
        __syncthreads();
    }
#pragma unroll
    for (int j = 0; j < 4; ++j) {
        int px = px0 + wv * 16 + (lane >> 4) * 4 + j;
#pragma unroll
        for (int ni = 0; ni < 2; ++ni) {
            int o = ni * 16 + (lane & 15);
            float bv = (o < 18) ? bias[o] : 0.f;
            offp[(size_t)px * 32 + o] = fmaxf(acc[ni][j] + bv, 0.f);
        }
    }
}

// ---------------------------------------------------------------- dcn GEMM: 64px x 128o, fused bilinear, dbuf
__global__ __launch_bounds__(256) void k_dcng(const unsigned short* __restrict__ xth,
                                              const float* __restrict__ offp,
                                              const unsigned short* __restrict__ wbd,
                                              const float* __restrict__ xn,
                                              float* __restrict__ out) {
    __shared__ short S_s[2][64 * 64];    // samples [px][64k] swizzled
    __shared__ short W_s[2][128 * 64];   // weights [o][64k] swizzled
    const int tid = threadIdx.x;
    const int px0 = blockIdx.x * 64;
    const int oblk = blockIdx.y;
    const int b = px0 >> 12;
    const unsigned short* xb = xth + (size_t)b * HPIX * 256;

    const unsigned short* wbase[4];
#pragma unroll
    for (int i = 0; i < 4; ++i) {
        int u = i * 256 + tid;
        int ol = u >> 3;
        wbase[i] = wbd + (size_t)(oblk * 128 + ol) * Kdim + swz(u);
    }
    const int kswz = swz(tid);           // same for both px slots

    int pofs[2][4];
    float wgt[2][4];

    const int lane = tid & 63, wv = tid >> 6;
    const int wm = wv >> 1, wn = wv & 1;  // wave tile: 64o x 32px
    f32x4 acc[4][2] = {};

    auto STAGE = [&](int s, int buf) {
        int tap = s >> 2, chunk = s & 3;
        if (chunk == 0) {
            int ky = tap / 3 - 1, kx = tap % 3 - 1;
#pragma unroll
            for (int slot = 0; slot < 2; ++slot) {
                int pxl = (tid >> 3) + slot * 32;
                int px = px0 + pxl;
                int y = (px & 4095) >> 6, x = px & 63;
                float dyo = offp[(size_t)px * 32 + 2 * tap];
                float dxo = offp[(size_t)px * 32 + 2 * tap + 1];
                float ypos = (float)(y + ky) + dyo;
                float xpos = (float)(x + kx) + dxo;
                float y0f = floorf(ypos), x0f = floorf(xpos);
                float wy = ypos - y0f, wx = xpos - x0f;
                int y0 = (int)y0f, x0 = (int)x0f;
                bool y0v = (y0 >= 0) && (y0 < Hh), y1v = (y0 + 1 >= 0) && (y0 + 1 < Hh);
                bool x0v = (x0 >= 0) && (x0 < Wwd), x1v = (x0 + 1 >= 0) && (x0 + 1 < Wwd);
                int hy0 = min(max(y0, -1), 64) + 1, hy1 = min(max(y0 + 1, -1), 64) + 1;
                int hx0 = min(max(x0, -1), 64) + 1, hx1 = min(max(x0 + 1, -1), 64) + 1;
                wgt[slot][0] = (1.f - wy) * (1.f - wx) * (float)(y0v && x0v);
                wgt[slot][1] = (1.f - wy) * wx * (float)(y0v && x1v);
                wgt[slot][2] = wy * (1.f - wx) * (float)(y1v && x0v);
                wgt[slot][3] = wy * wx * (float)(y1v && x1v);
                pofs[slot][0] = (hy0 * HH + hx0) * 256;
                pofs[slot][1] = (hy0 * HH + hx1) * 256;
                pofs[slot][2] = (hy1 * HH + hx0) * 256;
                pofs[slot][3] = (hy1 * HH + hx1) * 256;
            }
        }
        short* Wb = &W_s[buf][0];
#pragma unroll
        for (int i = 0; i < 4; ++i) gload_lds16(wbase[i] + s * 64, Wb + (i * 256 + tid) * 8);
        short* Sb = &S_s[buf][0];
        const int cb = chunk * 64 + kswz;
#pragma unroll
        for (int slot = 0; slot < 2; ++slot) {
            const unsigned short* q = xb + cb;
            u32x4 u00 = *(const u32x4*)(q + pofs[slot][0]);
            u32x4 u01 = *(const u32x4*)(q + pofs[slot][1]);
            u32x4 u10 = *(const u32x4*)(q + pofs[slot][2]);
            u32x4 u11 = *(const u32x4*)(q + pofs[slot][3]);
            float w00 = wgt[slot][0], w01 = wgt[slot][1], w10 = wgt[slot][2], w11 = wgt[slot][3];
            u32x4 res;
#pragma unroll
            for (int qd = 0; qd < 4; ++qd) {
                float lo = w00 * bflo(u00[qd]) + w01 * bflo(u01[qd]) + w10 * bflo(u10[qd]) + w11 * bflo(u11[qd]);
                float hi = w00 * bfhi(u00[qd]) + w01 * bfhi(u01[qd]) + w10 * bfhi(u10[qd]) + w11 * bfhi(u11[qd]);
                res[qd] = (unsigned)f2bf(lo) | ((unsigned)f2bf(hi) << 16);
            }
            *(u32x4*)&Sb[(slot * 256 + tid) * 8] = res;
        }
    };

    STAGE(0, 0);
    __syncthreads();
    for (int s = 0; s < NSTEP; ++s) {
        int cur = s & 1;
        if (s + 1 < NSTEP) STAGE(s + 1, cur ^ 1);
        const short* Wb = &W_s[cur][0];
        const short* Sb = &S_s[cur][0];
        short8v wf[4][2], sf[2][2];
#pragma unroll
        for (int mi = 0; mi < 4; ++mi) {
            int row = wm * 64 + mi * 16 + (lane & 15);
#pragma unroll
            for (int kf = 0; kf < 2; ++kf) {
                int c8 = kf * 4 + (lane >> 4);
                wf[mi][kf] = *(const short8v*)&Wb[row * 64 + ((c8 ^ (row & 7)) << 3)];
            }
        }
#pragma unroll
        for (int ni = 0; ni < 2; ++ni) {
            int row = wn * 32 + ni * 16 + (lane & 15);
#pragma unroll
            for (int kf = 0; kf < 2; ++kf) {
                int c8 = kf * 4 + (lane >> 4);
                sf[ni][kf] = *(const short8v*)&Sb[row * 64 + ((c8 ^ (row & 7)) << 3)];
            }
        }
#pragma unroll
        for (int kf = 0; kf < 2; ++kf)
#pragma unroll
            for (int mi = 0; mi < 4; ++mi)
#pragma unroll
                for (int ni = 0; ni < 2; ++ni)
                    acc[mi][ni] = __builtin_amdgcn_mfma_f32_16x16x32_bf16(wf[mi][kf], sf[ni][kf],
                                                                          acc[mi][ni], 0, 0, 0);
        __syncthreads();
    }
#pragma unroll
    for (int mi = 0; mi < 4; ++mi) {
        int o = oblk * 128 + wm * 64 + mi * 16 + (lane >> 4) * 4;
#pragma unroll
        for (int j = 0; j < 4; ++j) {
            size_t rowbase = ((size_t)b * 256 + o + j) * HWp;
#pragma unroll
            for (int ni = 0; ni < 2; ++ni) {
                int px = px0 + wn * 32 + ni * 16 + (lane & 15);
                size_t idx = rowbase + (px & 4095);
                out[idx] = 0.5f * (xn[idx] + fmaxf(acc[mi][ni][j], 0.f));
            }
        }
    }
}

extern "C" void kernel_launch(void* const* d_in, const int* in_sizes, int n_in,
                              void* d_out, int out_size, void* d_ws, size_t ws_size,
                              hipStream_t stream) {
    const float* x_ref  = (const float*)d_in[0];
    const float* x_next = (const float*)d_in[1];
    const float* w1 = (const float*)d_in[2];
    const float* b1 = (const float*)d_in[3];
    const float* w2 = (const float*)d_in[4];
    const float* b2 = (const float*)d_in[5];
    const float* w3 = (const float*)d_in[6];
    const float* b3 = (const float*)d_in[7];
    const float* wd = (const float*)d_in[8];
    float* out = (float*)d_out;
    char* ws = (char*)d_ws;

    unsigned short* h1h = (unsigned short*)(ws + B_H1H);
    unsigned short* h2h = (unsigned short*)(ws + B_H2H);
    unsigned short* xth = (unsigned short*)(ws + B_XTH);
    float* prod = (float*)(ws + B_PROD);
    float* corr = (float*)(ws + B_CORR);
    float* offp = (float*)(ws + B_OFFP);
    unsigned short* wb2 = (unsigned short*)(ws + B_WB2);
    unsigned short* wbd = (unsigned short*)(ws + B_WBD);
    unsigned short* wb3 = (unsigned short*)(ws + B_WB3);

    k_zero_ring<<<12 * 260, 128, 0, stream>>>(h1h, h2h, xth);
    k_prod<<<NPIX / 64, 256, 0, stream>>>(x_next, x_ref, prod);
    k_corr<<<NPIX / 256, 256, 0, stream>>>(prod, corr);
    k_conv1<<<NPIX / 32, 256, 0, stream>>>(corr, w1, b1, h1h);
    k_xth<<<dim3(128, 8, Bsz), dim3(32, 8), 0, stream>>>(x_ref, xth);
    k_pack<<<(256 * Kdim) / 256, 256, 0, stream>>>(w2, wb2, 256);
    k_pack<<<(256 * Kdim) / 256, 256, 0, stream>>>(wd, wbd, 256);
    k_pack<<<(32 * Kdim) / 256, 256, 0, stream>>>(w3, wb3, 18);
    k_conv2g<<<dim3(256, 2), 256, 0, stream>>>(h1h, wb2, b2, h2h);
    k_conv3g<<<256, 256, 0, stream>>>(h2h, wb3, b3, offp);
    k_dcng<<<dim3(256, 2), 256, 0, stream>>>(xth, offp, wbd, x_next, out);
}

// Round 4
// 154.583 us; speedup vs baseline: 24.2288x; 1.0137x over previous
//
#include <hip/hip_runtime.h>

typedef __attribute__((ext_vector_type(8))) short short8v;
typedef __attribute__((ext_vector_type(4))) float f32x4;
typedef __attribute__((ext_vector_type(4))) unsigned int u32x4;

constexpr int Bsz = 4;
constexpr int Hh = 64, Wwd = 64;
constexpr int HWp = Hh * Wwd;            // 4096
constexpr int NPIX = Bsz * HWp;          // 16384
constexpr int HH = 66;                   // halo dim
constexpr int HPIX = HH * HH;            // 4356
constexpr int Kdim = 2304;               // 9*256
constexpr int NSTEP = 36;                // Kdim / 64

// ---- workspace byte offsets
constexpr size_t B_H1H  = 0;
constexpr size_t HALO_BYTES = (size_t)Bsz * HPIX * 256 * 2;      // 8,921,088
constexpr size_t B_H2H  = B_H1H + HALO_BYTES;
constexpr size_t B_XTH  = B_H2H + HALO_BYTES;
constexpr size_t B_PROD = B_XTH + HALO_BYTES;
constexpr size_t B_CORR = B_PROD + (size_t)NPIX * 4;
constexpr size_t B_OFFP = B_CORR + (size_t)NPIX * 4;
constexpr size_t B_WB2  = B_OFFP + (size_t)NPIX * 32 * 4;
constexpr size_t B_WBD  = B_WB2 + (size_t)256 * Kdim * 2;
constexpr size_t B_WB3  = B_WBD + (size_t)256 * Kdim * 2;

static __device__ __forceinline__ unsigned short f2bf(float f) {
    unsigned u = __builtin_bit_cast(unsigned, f);
    u += 0x7FFFu + ((u >> 16) & 1u);
    return (unsigned short)(u >> 16);
}
static __device__ __forceinline__ float bflo(unsigned u) {
    return __builtin_bit_cast(float, u << 16);
}
static __device__ __forceinline__ float bfhi(unsigned u) {
    return __builtin_bit_cast(float, u & 0xFFFF0000u);
}
static __device__ __forceinline__ unsigned cvt_pk_bf16(float lo, float hi) {
    unsigned r;
    asm("v_cvt_pk_bf16_f32 %0, %1, %2" : "=v"(r) : "v"(lo), "v"(hi));
    return r;
}
static __device__ __forceinline__ void gload_lds16(const void* g, void* l) {
    __builtin_amdgcn_global_load_lds((const __attribute__((address_space(1))) unsigned int*)g,
                                     (__attribute__((address_space(3))) unsigned int*)l, 16, 0, 0);
}
// T2 swizzle: 16B-unit u -> short offset of that unit's data within its 64-k row
static __device__ __forceinline__ int swz(int u) {
    return (((u & 7) ^ ((u >> 3) & 7)) << 3);
}

// ---------------------------------------------------------------- zero halo rings only
__global__ void k_zero_ring(unsigned short* h1h, unsigned short* h2h, unsigned short* xth) {
    int blk = blockIdx.x;             // 12 images * 260 ring px
    int img = blk / 260;
    int rp = blk - img * 260;
    int buf = img >> 2, b = img & 3;
    int y, x;
    if (rp < 66) { y = 0; x = rp; }
    else if (rp < 132) { y = 65; x = rp - 66; }
    else { int s2 = rp - 132; y = 1 + (s2 >> 1); x = (s2 & 1) * 65; }
    unsigned short* base = (buf == 0) ? h1h : (buf == 1) ? h2h : xth;
    unsigned* p = (unsigned*)(base + ((size_t)b * HPIX + y * HH + x) * 256);
    p[threadIdx.x] = 0;               // 128 threads x 4B = 512B (256 ch bf16)
}

// ---------------------------------------------------------------- prod
__global__ void k_prod(const float* __restrict__ xn, const float* __restrict__ xr,
                       float* __restrict__ prod) {
    __shared__ float red[4][64];
    int px0 = blockIdx.x * 64;
    int b = px0 >> 12;
    int pxl = threadIdx.x & 63, cg = threadIdx.x >> 6;
    size_t base = (size_t)b * 256 * HWp + (px0 & 4095) + pxl;
    const float* a = xn + base;
    const float* r = xr + base;
    float s = 0.f;
#pragma unroll 8
    for (int c = cg * 64; c < cg * 64 + 64; ++c)
        s += a[(size_t)c * HWp] * r[(size_t)c * HWp];
    red[cg][pxl] = s;
    __syncthreads();
    if (cg == 0)
        prod[px0 + pxl] = red[0][pxl] + red[1][pxl] + red[2][pxl] + red[3][pxl];
}

// ---------------------------------------------------------------- corr
__global__ void k_corr(const float* __restrict__ prod, float* __restrict__ corr) {
    int p = blockIdx.x * blockDim.x + threadIdx.x;
    if (p >= NPIX) return;
    int b = p >> 12, yx = p & 4095, y = yx >> 6, x = yx & 63;
    float s = 0.f;
    for (int dy = -1; dy <= 1; ++dy) {
        int yy = y + dy;
        if (yy < 0 || yy >= Hh) continue;
        for (int dx = -1; dx <= 1; ++dx) {
            int xx = x + dx;
            if (xx < 0 || xx >= Wwd) continue;
            s += prod[b * HWp + yy * Wwd + xx];
        }
    }
    s *= (1.0f / 256.0f);
    corr[p] = (s > 0.f) ? s : 0.1f * s;
}

// ---------------------------------------------------------------- conv1 (Cin=1) -> h1h NHWC halo bf16
__global__ __launch_bounds__(256) void k_conv1(const float* __restrict__ corr,
                                               const float* __restrict__ w1,
                                               const float* __restrict__ b1,
                                               unsigned short* __restrict__ h1h) {
    __shared__ float pt[3][34];
    int px0 = blockIdx.x * 32;
    int b = px0 >> 12, y = (px0 & 4095) >> 6, x0 = px0 & 63;
    int tid = threadIdx.x;
    if (tid < 102) {
        int i = tid / 34, j = tid - i * 34;
        int yy = y - 1 + i, xx = x0 - 1 + j;
        float v = 0.f;
        if (yy >= 0 && yy < Hh && xx >= 0 && xx < Wwd) v = corr[b * HWp + yy * Wwd + xx];
        pt[i][j] = v;
    }
    float wl[9];
#pragma unroll
    for (int k = 0; k < 9; ++k) wl[k] = w1[tid * 9 + k];
    float bias = b1[tid];
    __syncthreads();
    for (int p = 0; p < 32; ++p) {
        float acc = bias;
#pragma unroll
        for (int ky = 0; ky < 3; ++ky)
#pragma unroll
            for (int kx = 0; kx < 3; ++kx) acc = fmaf(pt[ky][p + kx], wl[ky * 3 + kx], acc);
        acc = fmaxf(acc, 0.f);
        h1h[((size_t)b * HPIX + (y + 1) * HH + (x0 + p + 1)) * 256 + tid] = f2bf(acc);
    }
}

// ---------------------------------------------------------------- x_ref NCHW f32 -> NHWC halo bf16
__global__ void k_xth(const float* __restrict__ in, unsigned short* __restrict__ out) {
    __shared__ float t[32][33];
    int b = blockIdx.z;
    int c0 = blockIdx.y * 32;
    int y = blockIdx.x >> 1, x0 = (blockIdx.x & 1) * 32;
    int tx = threadIdx.x, ty = threadIdx.y;  // 32 x 8
#pragma unroll
    for (int i = 0; i < 32; i += 8)
        t[ty + i][tx] = in[((size_t)b * 256 + c0 + ty + i) * HWp + y * Wwd + x0 + tx];
    __syncthreads();
#pragma unroll
    for (int i = 0; i < 32; i += 8)
        out[((size_t)b * HPIX + (y + 1) * HH + (x0 + ty + i + 1)) * 256 + c0 + tx] =
            f2bf(t[tx][ty + i]);
}

// ---------------------------------------------------------------- weight pack [O][C][9] -> [o][tap*256+c] bf16
__global__ void k_pack(const float* __restrict__ w, unsigned short* __restrict__ out, int O_in) {
    int i = blockIdx.x * 256 + threadIdx.x;
    int o = i / Kdim;
    int r = i - o * Kdim;
    int k = r >> 8, c = r & 255;
    float v = (o < O_in) ? w[((size_t)o * 256 + c) * 9 + k] : 0.f;
    out[i] = f2bf(v);
}

// ---------------------------------------------------------------- conv2 GEMM: 64px x 128o tile, BK=64, dbuf
__global__ __launch_bounds__(256) void k_conv2g(const unsigned short* __restrict__ h1h,
                                                const unsigned short* __restrict__ wb,
                                                const float* __restrict__ bias,
                                                unsigned short* __restrict__ h2h) {
    __shared__ short A_s[2][64 * 64];
    __shared__ short B_s[2][128 * 64];
    const int tid = threadIdx.x;
    const int px0 = blockIdx.x * 64;
    const int oblk = blockIdx.y;
    const int b = px0 >> 12;
    const unsigned short* hb = h1h + (size_t)b * HPIX * 256;

    const unsigned short* abase[2];
#pragma unroll
    for (int i = 0; i < 2; ++i) {
        int u = i * 256 + tid;
        int pxl = u >> 3;
        int pxg = px0 + pxl;
        int y = (pxg & 4095) >> 6, x = pxg & 63;
        abase[i] = hb + (size_t)((y + 1) * HH + (x + 1)) * 256 + swz(u);
    }
    const unsigned short* bbase[4];
#pragma unroll
    for (int i = 0; i < 4; ++i) {
        int u = i * 256 + tid;
        int ol = u >> 3;
        bbase[i] = wb + (size_t)(oblk * 128 + ol) * Kdim + swz(u);
    }

    const int lane = tid & 63, wv = tid >> 6;
    const int wm = wv >> 1, wn = wv & 1;     // wave tile: 32px x 64o
    f32x4 acc[2][4] = {};

    auto STAGE = [&](int s, int buf) {
        int tap = s >> 2, chunk = s & 3;
        int delta = ((tap / 3 - 1) * HH + (tap % 3 - 1)) * 256 + chunk * 64;
        short* Ab = &A_s[buf][0];
        short* Bb = &B_s[buf][0];
#pragma unroll
        for (int i = 0; i < 2; ++i) gload_lds16(abase[i] + delta, Ab + (i * 256 + tid) * 8);
#pragma unroll
        for (int i = 0; i < 4; ++i) gload_lds16(bbase[i] + s * 64, Bb + (i * 256 + tid) * 8);
    };

    STAGE(0, 0);
    __syncthreads();
    for (int s = 0; s < NSTEP; ++s) {
        int cur = s & 1;
        if (s + 1 < NSTEP) STAGE(s + 1, cur ^ 1);
        const short* Ab = &A_s[cur][0];
        const short* Bb = &B_s[cur][0];
        short8v af[2][2], bf[4][2];
#pragma unroll
        for (int mi = 0; mi < 2; ++mi) {
            int row = wm * 32 + mi * 16 + (lane & 15);
#pragma unroll
            for (int kf = 0; kf < 2; ++kf) {
                int c8 = kf * 4 + (lane >> 4);
                af[mi][kf] = *(const short8v*)&Ab[row * 64 + ((c8 ^ (row & 7)) << 3)];
            }
        }
#pragma unroll
        for (int ni = 0; ni < 4; ++ni) {
            int row = wn * 64 + ni * 16 + (lane & 15);
#pragma unroll
            for (int kf = 0; kf < 2; ++kf) {
                int c8 = kf * 4 + (lane >> 4);
                bf[ni][kf] = *(const short8v*)&Bb[row * 64 + ((c8 ^ (row & 7)) << 3)];
            }
        }
#pragma unroll
        for (int kf = 0; kf < 2; ++kf)
#pragma unroll
            for (int mi = 0; mi < 2; ++mi)
#pragma unroll
                for (int ni = 0; ni < 4; ++ni)
                    acc[mi][ni] = __builtin_amdgcn_mfma_f32_16x16x32_bf16(af[mi][kf], bf[ni][kf],
                                                                          acc[mi][ni], 0, 0, 0);
        __syncthreads();
    }
#pragma unroll
    for (int mi = 0; mi < 2; ++mi) {
#pragma unroll
        for (int j = 0; j < 4; ++j) {
            int px = px0 + wm * 32 + mi * 16 + (lane >> 4) * 4 + j;
            int y = (px & 4095) >> 6, x = px & 63;
            unsigned short* dst = h2h + ((size_t)b * HPIX + (y + 1) * HH + (x + 1)) * 256;
#pragma unroll
            for (int ni = 0; ni < 4; ++ni) {
                int o = oblk * 128 + wn * 64 + ni * 16 + (lane & 15);
                dst[o] = f2bf(fmaxf(acc[mi][ni][j] + bias[o], 0.f));
            }
        }
    }
}

// ---------------------------------------------------------------- conv3 GEMM: 64px x 32o, BK=64, dbuf
__global__ __launch_bounds__(256) void k_conv3g(const unsigned short* __restrict__ h2h,
                                                const unsigned short* __restrict__ wb,
                                                const float* __restrict__ bias,
                                                float* __restrict__ offp) {
    __shared__ short A_s[2][64 * 64];
    __shared__ short B_s[2][32 * 64];
    const int tid = threadIdx.x;
    const int px0 = blockIdx.x * 64;
    const int b = px0 >> 12;
    const unsigned short* hb = h2h + (size_t)b * HPIX * 256;

    const unsigned short* abase[2];
#pragma unroll
    for (int i = 0; i < 2; ++i) {
        int u = i * 256 + tid;
        int pxl = u >> 3;
        int pxg = px0 + pxl;
        int y = (pxg & 4095) >> 6, x = pxg & 63;
        abase[i] = hb + (size_t)((y + 1) * HH + (x + 1)) * 256 + swz(u);
    }
    const unsigned short* bbase = wb + (size_t)(tid >> 3) * Kdim + swz(tid);

    const int lane = tid & 63, wv = tid >> 6;   // wave tile: 16px x 32o
    f32x4 acc[2] = {};

    auto STAGE = [&](int s, int buf) {
        int tap = s >> 2, chunk = s & 3;
        int delta = ((tap / 3 - 1) * HH + (tap % 3 - 1)) * 256 + chunk * 64;
        short* Ab = &A_s[buf][0];
#pragma unroll
        for (int i = 0; i < 2; ++i) gload_lds16(abase[i] + delta, Ab + (i * 256 + tid) * 8);
        gload_lds16(bbase + s * 64, &B_s[buf][tid * 8]);
    };

    STAGE(0, 0);
    __syncthreads();
    for (int s = 0; s < NSTEP; ++s) {
        int cur = s & 1;
        if (s + 1 < NSTEP) STAGE(s + 1, cur ^ 1);
        const short* Ab = &A_s[cur][0];
        const short* Bb = &B_s[cur][0];
        short8v af[2], bf[2][2];
#pragma unroll
        for (int kf = 0; kf < 2; ++kf) {
            int row = wv * 16 + (lane & 15);
            int c8 = kf * 4 + (lane >> 4);
            af[kf] = *(const short8v*)&Ab[row * 64 + ((c8 ^ (row & 7)) << 3)];
        }
#pragma unroll
        for (int ni = 0; ni < 2; ++ni) {
            int row = ni * 16 + (lane & 15);
#pragma unroll
            for (int kf = 0; kf < 2; ++kf) {
                int c8 = kf * 4 + (lane >> 4);
                bf[ni][kf] = *(const short8v*)&Bb[row * 64 + ((c8 ^ (row & 7)) << 3)];
            }
        }
#pragma unroll
        for (int kf = 0; kf < 2; ++kf)
#pragma unroll
            for (int ni = 0; ni < 2; ++ni)
                acc[ni] = __builtin_amdgcn_mfma_f32_16x16x32_bf16(af[kf], bf[ni][kf], acc[ni], 0, 0, 0);
        __syncthreads();
    }
#pragma unroll
    for (int j = 0; j < 4; ++j) {
        int px = px0 + wv * 16 + (lane >> 4) * 4 + j;
#pragma unroll
        for (int ni = 0; ni < 2; ++ni) {
            int o = ni * 16 + (lane & 15);
            float bv = (o < 18) ? bias[o] : 0.f;
            offp[(size_t)px * 32 + o] = fmaxf(acc[ni][j] + bv, 0.f);
        }
    }
}

// ---------------------------------------------------------------- dcn GEMM: 32px x 128o, fused bilinear
// 1024 blocks, 40 KB LDS -> 4 blocks/CU; T14 ordering; 4 gathers in flight.
__global__ __launch_bounds__(256, 4) void k_dcng(const unsigned short* __restrict__ xth,
                                                 const float* __restrict__ offp,
                                                 const unsigned short* __restrict__ wbd,
                                                 const float* __restrict__ xn,
                                                 float* __restrict__ out) {
    __shared__ short S_s[2][32 * 64];    // samples [px][64k] swizzled, 4 KB/buf
    __shared__ short W_s[2][128 * 64];   // weights [o][64k] swizzled, 16 KB/buf
    const int tid = threadIdx.x;
    const int px0 = blockIdx.x * 32;
    const int oblk = blockIdx.y;
    const int b = px0 >> 12;
    const unsigned short* xb = xth + (size_t)b * HPIX * 256;
    const int pxl = tid >> 3;            // 32 px, 8 threads each
    const int px = px0 + pxl;
    const int y = (px & 4095) >> 6, x = px & 63;
    const int ks = ((tid & 7) ^ (pxl & 7)) << 3;   // swizzled k-offset (shorts)
    // W staging: unit u = r*256+tid -> o = r*32 + (tid>>3); swizzle constant in r
    const unsigned short* wb0 = wbd + (size_t)(oblk * 128 + pxl) * Kdim + ks;

    const int lane = tid & 63, wv = tid >> 6;
    const int wm = wv >> 1, wn = wv & 1;  // wave tile: 64o x 16px
    f32x4 acc[4] = {};

    int pofs[4];
    float wgt[4];
    u32x4 g00, g01, g10, g11;

    auto SETUP = [&](int tap) {
        int ky = tap / 3 - 1, kx = tap % 3 - 1;
        float dyo = offp[(size_t)px * 32 + 2 * tap];
        float dxo = offp[(size_t)px * 32 + 2 * tap + 1];
        float ypos = (float)(y + ky) + dyo;
        float xpos = (float)(x + kx) + dxo;
        float y0f = floorf(ypos), x0f = floorf(xpos);
        float wy = ypos - y0f, wx = xpos - x0f;
        int y0 = (int)y0f, x0 = (int)x0f;
        bool y0v = (y0 >= 0) && (y0 < Hh), y1v = (y0 + 1 >= 0) && (y0 + 1 < Hh);
        bool x0v = (x0 >= 0) && (x0 < Wwd), x1v = (x0 + 1 >= 0) && (x0 + 1 < Wwd);
        int hy0 = min(max(y0, -1), 64) + 1, hy1 = min(max(y0 + 1, -1), 64) + 1;
        int hx0 = min(max(x0, -1), 64) + 1, hx1 = min(max(x0 + 1, -1), 64) + 1;
        wgt[0] = (1.f - wy) * (1.f - wx) * (float)(y0v && x0v);
        wgt[1] = (1.f - wy) * wx * (float)(y0v && x1v);
        wgt[2] = wy * (1.f - wx) * (float)(y1v && x0v);
        wgt[3] = wy * wx * (float)(y1v && x1v);
        pofs[0] = (hy0 * HH + hx0) * 256;
        pofs[1] = (hy0 * HH + hx1) * 256;
        pofs[2] = (hy1 * HH + hx0) * 256;
        pofs[3] = (hy1 * HH + hx1) * 256;
    };
    auto GATHER = [&](int chunk) {
        const unsigned short* q = xb + chunk * 64 + ks;
        g00 = *(const u32x4*)(q + pofs[0]);
        g01 = *(const u32x4*)(q + pofs[1]);
        g10 = *(const u32x4*)(q + pofs[2]);
        g11 = *(const u32x4*)(q + pofs[3]);
    };
    auto WSTAGE = [&](int s, int buf) {
        short* Wb = &W_s[buf][0];
#pragma unroll
        for (int r = 0; r < 4; ++r)
            gload_lds16(wb0 + (size_t)(32 * r) * Kdim + s * 64, Wb + (r * 256 + tid) * 8);
    };
    auto COMBINE = [&](int buf) {
        u32x4 res;
#pragma unroll
        for (int qd = 0; qd < 4; ++qd) {
            float lo = wgt[0] * bflo(g00[qd]) + wgt[1] * bflo(g01[qd]) +
                       wgt[2] * bflo(g10[qd]) + wgt[3] * bflo(g11[qd]);
            float hi = wgt[0] * bfhi(g00[qd]) + wgt[1] * bfhi(g01[qd]) +
                       wgt[2] * bfhi(g10[qd]) + wgt[3] * bfhi(g11[qd]);
            res[qd] = cvt_pk_bf16(lo, hi);
        }
        *(u32x4*)&S_s[buf][tid * 8] = res;
    };

    // prologue: stage step 0
    WSTAGE(0, 0);
    SETUP(0);
    GATHER(0);
    COMBINE(0);
    __syncthreads();

    for (int s = 0; s < NSTEP; ++s) {
        int cur = s & 1;
        if (s + 1 < NSTEP) {
            WSTAGE(s + 1, cur ^ 1);                    // async -> LDS
            int tap = (s + 1) >> 2, chunk = (s + 1) & 3;
            if (chunk == 0) SETUP(tap);
            GATHER(chunk);                              // loads in flight under MFMA
        }
        const short* Wb = &W_s[cur][0];
        const short* Sb = &S_s[cur][0];
        short8v wf[4][2], sf[2];
#pragma unroll
        for (int mi = 0; mi < 4; ++mi) {
            int row = wm * 64 + mi * 16 + (lane & 15);
#pragma unroll
            for (int kf = 0; kf < 2; ++kf) {
                int c8 = kf * 4 + (lane >> 4);
                wf[mi][kf] = *(const short8v*)&Wb[row * 64 + ((c8 ^ (row & 7)) << 3)];
            }
        }
        {
            int srow = wn * 16 + (lane & 15);
#pragma unroll
            for (int kf = 0; kf < 2; ++kf) {
                int c8 = kf * 4 + (lane >> 4);
                sf[kf] = *(const short8v*)&Sb[srow * 64 + ((c8 ^ (srow & 7)) << 3)];
            }
        }
#pragma unroll
        for (int kf = 0; kf < 2; ++kf)
#pragma unroll
            for (int mi = 0; mi < 4; ++mi)
                acc[mi] = __builtin_amdgcn_mfma_f32_16x16x32_bf16(wf[mi][kf], sf[kf], acc[mi], 0, 0, 0);
        if (s + 1 < NSTEP) COMBINE(cur ^ 1);
        __syncthreads();
    }

#pragma unroll
    for (int mi = 0; mi < 4; ++mi) {
        int o = oblk * 128 + wm * 64 + mi * 16 + (lane >> 4) * 4;
        int p2 = (px0 + wn * 16 + (lane & 15)) & 4095;
#pragma unroll
        for (int j = 0; j < 4; ++j) {
            size_t idx = ((size_t)b * 256 + o + j) * HWp + p2;
            out[idx] = 0.5f * (xn[idx] + fmaxf(acc[mi][j], 0.f));
        }
    }
}

extern "C" void kernel_launch(void* const* d_in, const int* in_sizes, int n_in,
                              void* d_out, int out_size, void* d_ws, size_t ws_size,
                              hipStream_t stream) {
    const float* x_ref  = (const float*)d_in[0];
    const float* x_next = (const float*)d_in[1];
    const float* w1 = (const float*)d_in[2];
    const float* b1 = (const float*)d_in[3];
    const float* w2 = (const float*)d_in[4];
    const float* b2 = (const float*)d_in[5];
    const float* w3 = (const float*)d_in[6];
    const float* b3 = (const float*)d_in[7];
    const float* wd = (const float*)d_in[8];
    float* out = (float*)d_out;
    char* ws = (char*)d_ws;

    unsigned short* h1h = (unsigned short*)(ws + B_H1H);
    unsigned short* h2h = (unsigned short*)(ws + B_H2H);
    unsigned short* xth = (unsigned short*)(ws + B_XTH);
    float* prod = (float*)(ws + B_PROD);
    float* corr = (float*)(ws + B_CORR);
    float* offp = (float*)(ws + B_OFFP);
    unsigned short* wb2 = (unsigned short*)(ws + B_WB2);
    unsigned short* wbd = (unsigned short*)(ws + B_WBD);
    unsigned short* wb3 = (unsigned short*)(ws + B_WB3);

    k_zero_ring<<<12 * 260, 128, 0, stream>>>(h1h, h2h, xth);
    k_prod<<<NPIX / 64, 256, 0, stream>>>(x_next, x_ref, prod);
    k_corr<<<NPIX / 256, 256, 0, stream>>>(prod, corr);
    k_conv1<<<NPIX / 32, 256, 0, stream>>>(corr, w1, b1, h1h);
    k_xth<<<dim3(128, 8, Bsz), dim3(32, 8), 0, stream>>>(x_ref, xth);
    k_pack<<<(256 * Kdim) / 256, 256, 0, stream>>>(w2, wb2, 256);
    k_pack<<<(256 * Kdim) / 256, 256, 0, stream>>>(wd, wbd, 256);
    k_pack<<<(32 * Kdim) / 256, 256, 0, stream>>>(w3, wb3, 18);
    k_conv2g<<<dim3(256, 2), 256, 0, stream>>>(h1h, wb2, b2, h2h);
    k_conv3g<<<256, 256, 0, stream>>>(h2h, wb3, b3, offp);
    k_dcng<<<dim3(512, 2), 256, 0, stream>>>(xth, offp, wbd, x_next, out);
}

// Round 5
// 148.606 us; speedup vs baseline: 25.2034x; 1.0402x over previous
//
#include <hip/hip_runtime.h>

typedef __attribute__((ext_vector_type(8))) short short8v;
typedef __attribute__((ext_vector_type(4))) float f32x4;
typedef __attribute__((ext_vector_type(2))) float f32x2;
typedef __attribute__((ext_vector_type(4))) unsigned int u32x4;

constexpr int Bsz = 4;
constexpr int Hh = 64, Wwd = 64;
constexpr int HWp = Hh * Wwd;            // 4096
constexpr int NPIX = Bsz * HWp;          // 16384
constexpr int HH = 66;                   // halo dim
constexpr int HPIX = HH * HH;            // 4356
constexpr int Kdim = 2304;               // 9*256
constexpr int NSTEP = 36;                // Kdim / 64

// ---- workspace byte offsets
constexpr size_t B_H1H  = 0;
constexpr size_t HALO_BYTES = (size_t)Bsz * HPIX * 256 * 2;      // 8,921,088
constexpr size_t B_H2H  = B_H1H + HALO_BYTES;
constexpr size_t B_XTH  = B_H2H + HALO_BYTES;
constexpr size_t B_PROD = B_XTH + HALO_BYTES;
constexpr size_t B_CORR = B_PROD + (size_t)NPIX * 4;
constexpr size_t B_OFFP = B_CORR + (size_t)NPIX * 4;
constexpr size_t B_WB2  = B_OFFP + (size_t)NPIX * 32 * 4;
constexpr size_t B_WBD  = B_WB2 + (size_t)256 * Kdim * 2;
constexpr size_t B_WB3  = B_WBD + (size_t)256 * Kdim * 2;

static __device__ __forceinline__ unsigned short f2bf(float f) {
    unsigned u = __builtin_bit_cast(unsigned, f);
    u += 0x7FFFu + ((u >> 16) & 1u);
    return (unsigned short)(u >> 16);
}
static __device__ __forceinline__ unsigned cvt_pk_bf16(float lo, float hi) {
    unsigned r;
    asm("v_cvt_pk_bf16_f32 %0, %1, %2" : "=v"(r) : "v"(lo), "v"(hi));
    return r;
}
static __device__ __forceinline__ f32x2 pk_mul(f32x2 a, f32x2 b) {
    f32x2 d;
    asm("v_pk_mul_f32 %0, %1, %2" : "=v"(d) : "v"(a), "v"(b));
    return d;
}
static __device__ __forceinline__ f32x2 pk_fma(f32x2 a, f32x2 b, f32x2 c) {
    f32x2 d;
    asm("v_pk_fma_f32 %0, %1, %2, %3" : "=v"(d) : "v"(a), "v"(b), "v"(c));
    return d;
}
static __device__ __forceinline__ f32x2 unpack2(unsigned u) {
    f32x2 v;
    v.x = __builtin_bit_cast(float, u << 16);
    v.y = __builtin_bit_cast(float, u & 0xFFFF0000u);
    return v;
}
static __device__ __forceinline__ void gload_lds16(const void* g, void* l) {
    __builtin_amdgcn_global_load_lds((const __attribute__((address_space(1))) unsigned int*)g,
                                     (__attribute__((address_space(3))) unsigned int*)l, 16, 0, 0);
}
// T2 swizzle: 16B-unit u -> short offset of that unit's data within its 64-k row
static __device__ __forceinline__ int swz(int u) {
    return (((u & 7) ^ ((u >> 3) & 7)) << 3);
}

// ---------------------------------------------------------------- zero halo rings only
__global__ void k_zero_ring(unsigned short* h1h, unsigned short* h2h, unsigned short* xth) {
    int blk = blockIdx.x;             // 12 images * 260 ring px
    int img = blk / 260;
    int rp = blk - img * 260;
    int buf = img >> 2, b = img & 3;
    int y, x;
    if (rp < 66) { y = 0; x = rp; }
    else if (rp < 132) { y = 65; x = rp - 66; }
    else { int s2 = rp - 132; y = 1 + (s2 >> 1); x = (s2 & 1) * 65; }
    unsigned short* base = (buf == 0) ? h1h : (buf == 1) ? h2h : xth;
    unsigned* p = (unsigned*)(base + ((size_t)b * HPIX + y * HH + x) * 256);
    p[threadIdx.x] = 0;               // 128 threads x 4B = 512B (256 ch bf16)
}

// ---------------------------------------------------------------- prod
__global__ void k_prod(const float* __restrict__ xn, const float* __restrict__ xr,
                       float* __restrict__ prod) {
    __shared__ float red[4][64];
    int px0 = blockIdx.x * 64;
    int b = px0 >> 12;
    int pxl = threadIdx.x & 63, cg = threadIdx.x >> 6;
    size_t base = (size_t)b * 256 * HWp + (px0 & 4095) + pxl;
    const float* a = xn + base;
    const float* r = xr + base;
    float s = 0.f;
#pragma unroll 8
    for (int c = cg * 64; c < cg * 64 + 64; ++c)
        s += a[(size_t)c * HWp] * r[(size_t)c * HWp];
    red[cg][pxl] = s;
    __syncthreads();
    if (cg == 0)
        prod[px0 + pxl] = red[0][pxl] + red[1][pxl] + red[2][pxl] + red[3][pxl];
}

// ---------------------------------------------------------------- corr
__global__ void k_corr(const float* __restrict__ prod, float* __restrict__ corr) {
    int p = blockIdx.x * blockDim.x + threadIdx.x;
    if (p >= NPIX) return;
    int b = p >> 12, yx = p & 4095, y = yx >> 6, x = yx & 63;
    float s = 0.f;
    for (int dy = -1; dy <= 1; ++dy) {
        int yy = y + dy;
        if (yy < 0 || yy >= Hh) continue;
        for (int dx = -1; dx <= 1; ++dx) {
            int xx = x + dx;
            if (xx < 0 || xx >= Wwd) continue;
            s += prod[b * HWp + yy * Wwd + xx];
        }
    }
    s *= (1.0f / 256.0f);
    corr[p] = (s > 0.f) ? s : 0.1f * s;
}

// ---------------------------------------------------------------- conv1 (Cin=1) -> h1h NHWC halo bf16
__global__ __launch_bounds__(256) void k_conv1(const float* __restrict__ corr,
                                               const float* __restrict__ w1,
                                               const float* __restrict__ b1,
                                               unsigned short* __restrict__ h1h) {
    __shared__ float pt[3][34];
    int px0 = blockIdx.x * 32;
    int b = px0 >> 12, y = (px0 & 4095) >> 6, x0 = px0 & 63;
    int tid = threadIdx.x;
    if (tid < 102) {
        int i = tid / 34, j = tid - i * 34;
        int yy = y - 1 + i, xx = x0 - 1 + j;
        float v = 0.f;
        if (yy >= 0 && yy < Hh && xx >= 0 && xx < Wwd) v = corr[b * HWp + yy * Wwd + xx];
        pt[i][j] = v;
    }
    float wl[9];
#pragma unroll
    for (int k = 0; k < 9; ++k) wl[k] = w1[tid * 9 + k];
    float bias = b1[tid];
    __syncthreads();
    for (int p = 0; p < 32; ++p) {
        float acc = bias;
#pragma unroll
        for (int ky = 0; ky < 3; ++ky)
#pragma unroll
            for (int kx = 0; kx < 3; ++kx) acc = fmaf(pt[ky][p + kx], wl[ky * 3 + kx], acc);
        acc = fmaxf(acc, 0.f);
        h1h[((size_t)b * HPIX + (y + 1) * HH + (x0 + p + 1)) * 256 + tid] = f2bf(acc);
    }
}

// ---------------------------------------------------------------- x_ref NCHW f32 -> NHWC halo bf16
__global__ void k_xth(const float* __restrict__ in, unsigned short* __restrict__ out) {
    __shared__ float t[32][33];
    int b = blockIdx.z;
    int c0 = blockIdx.y * 32;
    int y = blockIdx.x >> 1, x0 = (blockIdx.x & 1) * 32;
    int tx = threadIdx.x, ty = threadIdx.y;  // 32 x 8
#pragma unroll
    for (int i = 0; i < 32; i += 8)
        t[ty + i][tx] = in[((size_t)b * 256 + c0 + ty + i) * HWp + y * Wwd + x0 + tx];
    __syncthreads();
#pragma unroll
    for (int i = 0; i < 32; i += 8)
        out[((size_t)b * HPIX + (y + 1) * HH + (x0 + ty + i + 1)) * 256 + c0 + tx] =
            f2bf(t[tx][ty + i]);
}

// ---------------------------------------------------------------- weight pack [O][C][9] -> [o][tap*256+c] bf16
__global__ void k_pack(const float* __restrict__ w, unsigned short* __restrict__ out, int O_in) {
    int i = blockIdx.x * 256 + threadIdx.x;
    int o = i / Kdim;
    int r = i - o * Kdim;
    int k = r >> 8, c = r & 255;
    float v = (o < O_in) ? w[((size_t)o * 256 + c) * 9 + k] : 0.f;
    out[i] = f2bf(v);
}

// ---------------------------------------------------------------- conv2 GEMM: 64px x 128o tile, BK=64, dbuf
__global__ __launch_bounds__(256) void k_conv2g(const unsigned short* __restrict__ h1h,
                                                const unsigned short* __restrict__ wb,
                                                const float* __restrict__ bias,
                                                unsigned short* __restrict__ h2h) {
    __shared__ short A_s[2][64 * 64];
    __shared__ short B_s[2][128 * 64];
    const int tid = threadIdx.x;
    const int px0 = blockIdx.x * 64;
    const int oblk = blockIdx.y;
    const int b = px0 >> 12;
    const unsigned short* hb = h1h + (size_t)b * HPIX * 256;

    const unsigned short* abase[2];
#pragma unroll
    for (int i = 0; i < 2; ++i) {
        int u = i * 256 + tid;
        int pxl = u >> 3;
        int pxg = px0 + pxl;
        int y = (pxg & 4095) >> 6, x = pxg & 63;
        abase[i] = hb + (size_t)((y + 1) * HH + (x + 1)) * 256 + swz(u);
    }
    const unsigned short* bbase[4];
#pragma unroll
    for (int i = 0; i < 4; ++i) {
        int u = i * 256 + tid;
        int ol = u >> 3;
        bbase[i] = wb + (size_t)(oblk * 128 + ol) * Kdim + swz(u);
    }

    const int lane = tid & 63, wv = tid >> 6;
    const int wm = wv >> 1, wn = wv & 1;     // wave tile: 32px x 64o
    f32x4 acc[2][4] = {};

    auto STAGE = [&](int s, int buf) {
        int tap = s >> 2, chunk = s & 3;
        int delta = ((tap / 3 - 1) * HH + (tap % 3 - 1)) * 256 + chunk * 64;
        short* Ab = &A_s[buf][0];
        short* Bb = &B_s[buf][0];
#pragma unroll
        for (int i = 0; i < 2; ++i) gload_lds16(abase[i] + delta, Ab + (i * 256 + tid) * 8);
#pragma unroll
        for (int i = 0; i < 4; ++i) gload_lds16(bbase[i] + s * 64, Bb + (i * 256 + tid) * 8);
    };

    STAGE(0, 0);
    __syncthreads();
    for (int s = 0; s < NSTEP; ++s) {
        int cur = s & 1;
        if (s + 1 < NSTEP) STAGE(s + 1, cur ^ 1);
        const short* Ab = &A_s[cur][0];
        const short* Bb = &B_s[cur][0];
        short8v af[2][2], bf[4][2];
#pragma unroll
        for (int mi = 0; mi < 2; ++mi) {
            int row = wm * 32 + mi * 16 + (lane & 15);
#pragma unroll
            for (int kf = 0; kf < 2; ++kf) {
                int c8 = kf * 4 + (lane >> 4);
                af[mi][kf] = *(const short8v*)&Ab[row * 64 + ((c8 ^ (row & 7)) << 3)];
            }
        }
#pragma unroll
        for (int ni = 0; ni < 4; ++ni) {
            int row = wn * 64 + ni * 16 + (lane & 15);
#pragma unroll
            for (int kf = 0; kf < 2; ++kf) {
                int c8 = kf * 4 + (lane >> 4);
                bf[ni][kf] = *(const short8v*)&Bb[row * 64 + ((c8 ^ (row & 7)) << 3)];
            }
        }
#pragma unroll
        for (int kf = 0; kf < 2; ++kf)
#pragma unroll
            for (int mi = 0; mi < 2; ++mi)
#pragma unroll
                for (int ni = 0; ni < 4; ++ni)
                    acc[mi][ni] = __builtin_amdgcn_mfma_f32_16x16x32_bf16(af[mi][kf], bf[ni][kf],
                                                                          acc[mi][ni], 0, 0, 0);
        __syncthreads();
    }
#pragma unroll
    for (int mi = 0; mi < 2; ++mi) {
#pragma unroll
        for (int j = 0; j < 4; ++j) {
            int px = px0 + wm * 32 + mi * 16 + (lane >> 4) * 4 + j;
            int y = (px & 4095) >> 6, x = px & 63;
            unsigned short* dst = h2h + ((size_t)b * HPIX + (y + 1) * HH + (x + 1)) * 256;
#pragma unroll
            for (int ni = 0; ni < 4; ++ni) {
                int o = oblk * 128 + wn * 64 + ni * 16 + (lane & 15);
                dst[o] = f2bf(fmaxf(acc[mi][ni][j] + bias[o], 0.f));
            }
        }
    }
}

// ---------------------------------------------------------------- conv3 GEMM: 64px x 32o, BK=64, dbuf
__global__ __launch_bounds__(256) void k_conv3g(const unsigned short* __restrict__ h2h,
                                                const unsigned short* __restrict__ wb,
                                                const float* __restrict__ bias,
                                                float* __restrict__ offp) {
    __shared__ short A_s[2][64 * 64];
    __shared__ short B_s[2][32 * 64];
    const int tid = threadIdx.x;
    const int px0 = blockIdx.x * 64;
    const int b = px0 >> 12;
    const unsigned short* hb = h2h + (size_t)b * HPIX * 256;

    const unsigned short* abase[2];
#pragma unroll
    for (int i = 0; i < 2; ++i) {
        int u = i * 256 + tid;
        int pxl = u >> 3;
        int pxg = px0 + pxl;
        int y = (pxg & 4095) >> 6, x = pxg & 63;
        abase[i] = hb + (size_t)((y + 1) * HH + (x + 1)) * 256 + swz(u);
    }
    const unsigned short* bbase = wb + (size_t)(tid >> 3) * Kdim + swz(tid);

    const int lane = tid & 63, wv = tid >> 6;   // wave tile: 16px x 32o
    f32x4 acc[2] = {};

    auto STAGE = [&](int s, int buf) {
        int tap = s >> 2, chunk = s & 3;
        int delta = ((tap / 3 - 1) * HH + (tap % 3 - 1)) * 256 + chunk * 64;
        short* Ab = &A_s[buf][0];
#pragma unroll
        for (int i = 0; i < 2; ++i) gload_lds16(abase[i] + delta, Ab + (i * 256 + tid) * 8);
        gload_lds16(bbase + s * 64, &B_s[buf][tid * 8]);
    };

    STAGE(0, 0);
    __syncthreads();
    for (int s = 0; s < NSTEP; ++s) {
        int cur = s & 1;
        if (s + 1 < NSTEP) STAGE(s + 1, cur ^ 1);
        const short* Ab = &A_s[cur][0];
        const short* Bb = &B_s[cur][0];
        short8v af[2], bf[2][2];
#pragma unroll
        for (int kf = 0; kf < 2; ++kf) {
            int row = wv * 16 + (lane & 15);
            int c8 = kf * 4 + (lane >> 4);
            af[kf] = *(const short8v*)&Ab[row * 64 + ((c8 ^ (row & 7)) << 3)];
        }
#pragma unroll
        for (int ni = 0; ni < 2; ++ni) {
            int row = ni * 16 + (lane & 15);
#pragma unroll
            for (int kf = 0; kf < 2; ++kf) {
                int c8 = kf * 4 + (lane >> 4);
                bf[ni][kf] = *(const short8v*)&Bb[row * 64 + ((c8 ^ (row & 7)) << 3)];
            }
        }
#pragma unroll
        for (int kf = 0; kf < 2; ++kf)
#pragma unroll
            for (int ni = 0; ni < 2; ++ni)
                acc[ni] = __builtin_amdgcn_mfma_f32_16x16x32_bf16(af[kf], bf[ni][kf], acc[ni], 0, 0, 0);
        __syncthreads();
    }
#pragma unroll
    for (int j = 0; j < 4; ++j) {
        int px = px0 + wv * 16 + (lane >> 4) * 4 + j;
#pragma unroll
        for (int ni = 0; ni < 2; ++ni) {
            int o = ni * 16 + (lane & 15);
            float bv = (o < 18) ? bias[o] : 0.f;
            offp[(size_t)px * 32 + o] = fmaxf(acc[ni][j] + bv, 0.f);
        }
    }
}

// ---------------------------------------------------------------- dcn GEMM: 32px x 256o (dedup), fused bilinear
// grid 512 XCD-swizzled; 72KB LDS -> 2 blocks/CU; tap-loop w/ chunk-imm gathers; pk_fma combine.
__global__ __launch_bounds__(256, 2) void k_dcng(const unsigned short* __restrict__ xth,
                                                 const float* __restrict__ offp,
                                                 const unsigned short* __restrict__ wbd,
                                                 const float* __restrict__ xn,
                                                 float* __restrict__ out) {
    __shared__ short S_s[2][32 * 64];    // samples [px][64k] swizzled, 4 KB/buf
    __shared__ short W_s[2][256 * 64];   // weights [o][64k] swizzled, 32 KB/buf
    const int tid = threadIdx.x;
    // XCD-aware bijective swizzle: 512 blocks -> 64 contiguous per XCD
    const int bid = blockIdx.x;
    const int px0 = ((bid & 7) * 64 + (bid >> 3)) * 32;
    const int b = px0 >> 12;
    const unsigned short* xb = xth + (size_t)b * HPIX * 256;
    const int pxl = tid >> 3;            // 32 px, 8 threads each
    const int px = px0 + pxl;
    const int y = (px & 4095) >> 6, x = px & 63;
    const int ks = ((tid & 7) ^ (pxl & 7)) << 3;   // swizzled k-offset (shorts)
    const unsigned short* wb0 = wbd + (size_t)pxl * Kdim + ks;  // row = r*32 + (tid>>3)
    const float2* offv = (const float2*)offp;      // [px][16] float2 (dy,dx) per tap

    const int lane = tid & 63, wv = tid >> 6;      // wave tile: 64o x 32px
    f32x4 acc[4][2] = {};

    const unsigned short* pcorner[4];
    f32x2 wpair[4];
    float dyn, dxn;                                 // prefetched next-tap offsets
    u32x4 g00, g01, g10, g11;

    auto SETUP = [&](int tap, float dyo, float dxo) {
        int ky = tap / 3 - 1, kx = tap % 3 - 1;
        float ypos = (float)(y + ky) + dyo;
        float xpos = (float)(x + kx) + dxo;
        float y0f = floorf(ypos), x0f = floorf(xpos);
        float wy = ypos - y0f, wx = xpos - x0f;
        int y0 = (int)y0f, x0 = (int)x0f;
        bool y0v = (y0 >= 0) && (y0 < Hh), y1v = (y0 + 1 >= 0) && (y0 + 1 < Hh);
        bool x0v = (x0 >= 0) && (x0 < Wwd), x1v = (x0 + 1 >= 0) && (x0 + 1 < Wwd);
        int hy0 = min(max(y0, -1), 64) + 1, hy1 = min(max(y0 + 1, -1), 64) + 1;
        int hx0 = min(max(x0, -1), 64) + 1, hx1 = min(max(x0 + 1, -1), 64) + 1;
        float w0 = (1.f - wy) * (1.f - wx) * (float)(y0v && x0v);
        float w1 = (1.f - wy) * wx * (float)(y0v && x1v);
        float w2 = wy * (1.f - wx) * (float)(y1v && x0v);
        float w3 = wy * wx * (float)(y1v && x1v);
        wpair[0] = (f32x2){w0, w0};
        wpair[1] = (f32x2){w1, w1};
        wpair[2] = (f32x2){w2, w2};
        wpair[3] = (f32x2){w3, w3};
        pcorner[0] = xb + (size_t)((hy0 * HH + hx0) * 256) + ks;
        pcorner[1] = xb + (size_t)((hy0 * HH + hx1) * 256) + ks;
        pcorner[2] = xb + (size_t)((hy1 * HH + hx0) * 256) + ks;
        pcorner[3] = xb + (size_t)((hy1 * HH + hx1) * 256) + ks;
    };
    auto WSTAGE = [&](int s, int buf) {
        short* Wb = &W_s[buf][0];
#pragma unroll
        for (int r = 0; r < 8; ++r)
            gload_lds16(wb0 + (size_t)(32 * r) * Kdim + s * 64, Wb + (r * 256 + tid) * 8);
    };
    auto COMBINE = [&](int buf) {
        u32x4 res;
#pragma unroll
        for (int qd = 0; qd < 4; ++qd) {
            f32x2 a = pk_mul(unpack2(g00[qd]), wpair[0]);
            a = pk_fma(unpack2(g01[qd]), wpair[1], a);
            a = pk_fma(unpack2(g10[qd]), wpair[2], a);
            a = pk_fma(unpack2(g11[qd]), wpair[3], a);
            res[qd] = cvt_pk_bf16(a.x, a.y);
        }
        *(u32x4*)&S_s[buf][tid * 8] = res;
    };

    // prologue
    WSTAGE(0, 0);
    {
        float2 o0 = offv[(size_t)px * 16 + 0];
        SETUP(0, o0.x, o0.y);
    }
    g00 = *(const u32x4*)pcorner[0];
    g01 = *(const u32x4*)pcorner[1];
    g10 = *(const u32x4*)pcorner[2];
    g11 = *(const u32x4*)pcorner[3];
    COMBINE(0);
    __syncthreads();

    for (int tap = 0; tap < 9; ++tap) {
#pragma unroll
        for (int chunk = 0; chunk < 4; ++chunk) {
            const int s = tap * 4 + chunk;
            const int cur = s & 1;
            const bool more = (s + 1 < NSTEP);
            if (more) WSTAGE(s + 1, cur ^ 1);
            if (chunk == 0 && tap < 8) {
                float2 on = offv[(size_t)px * 16 + tap + 1];
                dyn = on.x; dxn = on.y;
            }
            if (chunk == 3 && more) SETUP(tap + 1, dyn, dxn);
            if (more) {
                const int nc = (chunk + 1) & 3;     // compile-time in unrolled body
                g00 = *(const u32x4*)(pcorner[0] + nc * 64);
                g01 = *(const u32x4*)(pcorner[1] + nc * 64);
                g10 = *(const u32x4*)(pcorner[2] + nc * 64);
                g11 = *(const u32x4*)(pcorner[3] + nc * 64);
            }
            const short* Wb = &W_s[cur][0];
            const short* Sb = &S_s[cur][0];
#pragma unroll
            for (int kf = 0; kf < 2; ++kf) {
                const int c8 = kf * 4 + (lane >> 4);
                short8v wf[4], sf[2];
#pragma unroll
                for (int mi = 0; mi < 4; ++mi) {
                    int row = wv * 64 + mi * 16 + (lane & 15);
                    wf[mi] = *(const short8v*)&Wb[row * 64 + ((c8 ^ (row & 7)) << 3)];
                }
#pragma unroll
                for (int ni = 0; ni < 2; ++ni) {
                    int srow = ni * 16 + (lane & 15);
                    sf[ni] = *(const short8v*)&Sb[srow * 64 + ((c8 ^ (srow & 7)) << 3)];
                }
#pragma unroll
                for (int mi = 0; mi < 4; ++mi)
#pragma unroll
                    for (int ni = 0; ni < 2; ++ni)
                        acc[mi][ni] = __builtin_amdgcn_mfma_f32_16x16x32_bf16(wf[mi], sf[ni],
                                                                              acc[mi][ni], 0, 0, 0);
            }
            if (more) COMBINE(cur ^ 1);
            __syncthreads();
        }
    }

#pragma unroll
    for (int mi = 0; mi < 4; ++mi) {
        int o = wv * 64 + mi * 16 + (lane >> 4) * 4;
#pragma unroll
        for (int j = 0; j < 4; ++j) {
            size_t rowbase = ((size_t)b * 256 + o + j) * HWp;
#pragma unroll
            for (int ni = 0; ni < 2; ++ni) {
                int p2 = (px0 + ni * 16 + (lane & 15)) & 4095;
                size_t idx = rowbase + p2;
                out[idx] = 0.5f * (xn[idx] + fmaxf(acc[mi][ni][j], 0.f));
            }
        }
    }
}

extern "C" void kernel_launch(void* const* d_in, const int* in_sizes, int n_in,
                              void* d_out, int out_size, void* d_ws, size_t ws_size,
                              hipStream_t stream) {
    const float* x_ref  = (const float*)d_in[0];
    const float* x_next = (const float*)d_in[1];
    const float* w1 = (const float*)d_in[2];
    const float* b1 = (const float*)d_in[3];
    const float* w2 = (const float*)d_in[4];
    const float* b2 = (const float*)d_in[5];
    const float* w3 = (const float*)d_in[6];
    const float* b3 = (const float*)d_in[7];
    const float* wd = (const float*)d_in[8];
    float* out = (float*)d_out;
    char* ws = (char*)d_ws;

    unsigned short* h1h = (unsigned short*)(ws + B_H1H);
    unsigned short* h2h = (unsigned short*)(ws + B_H2H);
    unsigned short* xth = (unsigned short*)(ws + B_XTH);
    float* prod = (float*)(ws + B_PROD);
    float* corr = (float*)(ws + B_CORR);
    float* offp = (float*)(ws + B_OFFP);
    unsigned short* wb2 = (unsigned short*)(ws + B_WB2);
    unsigned short* wbd = (unsigned short*)(ws + B_WBD);
    unsigned short* wb3 = (unsigned short*)(ws + B_WB3);

    k_zero_ring<<<12 * 260, 128, 0, stream>>>(h1h, h2h, xth);
    k_prod<<<NPIX / 64, 256, 0, stream>>>(x_next, x_ref, prod);
    k_corr<<<NPIX / 256, 256, 0, stream>>>(prod, corr);
    k_conv1<<<NPIX / 32, 256, 0, stream>>>(corr, w1, b1, h1h);
    k_xth<<<dim3(128, 8, Bsz), dim3(32, 8), 0, stream>>>(x_ref, xth);
    k_pack<<<(256 * Kdim) / 256, 256, 0, stream>>>(w2, wb2, 256);
    k_pack<<<(256 * Kdim) / 256, 256, 0, stream>>>(wd, wbd, 256);
    k_pack<<<(32 * Kdim) / 256, 256, 0, stream>>>(w3, wb3, 18);
    k_conv2g<<<dim3(256, 2), 256, 0, stream>>>(h1h, wb2, b2, h2h);
    k_conv3g<<<256, 256, 0, stream>>>(h2h, wb3, b3, offp);
    k_dcng<<<512, 256, 0, stream>>>(xth, offp, wbd, x_next, out);
}

// Round 6
// 132.802 us; speedup vs baseline: 28.2026x; 1.1190x over previous
//
#include <hip/hip_runtime.h>

typedef __attribute__((ext_vector_type(8))) short short8v;
typedef __attribute__((ext_vector_type(4))) float f32x4;
typedef __attribute__((ext_vector_type(2))) float f32x2;
typedef __attribute__((ext_vector_type(4))) unsigned int u32x4;

constexpr int Bsz = 4;
constexpr int Hh = 64, Wwd = 64;
constexpr int HWp = Hh * Wwd;            // 4096
constexpr int NPIX = Bsz * HWp;          // 16384
constexpr int HH = 66;                   // halo dim
constexpr int HPIX = HH * HH;            // 4356
constexpr int Kdim = 2304;               // 9*256
constexpr int NSTEP = 36;                // Kdim / 64

// ---- workspace byte offsets
constexpr size_t B_H1H  = 0;
constexpr size_t HALO_BYTES = (size_t)Bsz * HPIX * 256 * 2;      // 8,921,088
constexpr size_t B_H2H  = B_H1H + HALO_BYTES;
constexpr size_t B_XTH  = B_H2H + HALO_BYTES;
constexpr size_t B_PROD = B_XTH + HALO_BYTES;
constexpr size_t B_CORR = B_PROD + (size_t)NPIX * 4;
constexpr size_t B_OFFP = B_CORR + (size_t)NPIX * 4;
constexpr size_t B_WB2  = B_OFFP + (size_t)NPIX * 32 * 4;        // packed frag layout
constexpr size_t B_WBD  = B_WB2 + (size_t)256 * Kdim * 2;        // packed frag layout
constexpr size_t B_WB3  = B_WBD + (size_t)256 * Kdim * 2;        // linear layout (conv3g)

static __device__ __forceinline__ unsigned short f2bf(float f) {
    unsigned u = __builtin_bit_cast(unsigned, f);
    u += 0x7FFFu + ((u >> 16) & 1u);
    return (unsigned short)(u >> 16);
}
static __device__ __forceinline__ unsigned cvt_pk_bf16(float lo, float hi) {
    unsigned r;
    asm("v_cvt_pk_bf16_f32 %0, %1, %2" : "=v"(r) : "v"(lo), "v"(hi));
    return r;
}
static __device__ __forceinline__ f32x2 pk_mul(f32x2 a, f32x2 b) {
    f32x2 d;
    asm("v_pk_mul_f32 %0, %1, %2" : "=v"(d) : "v"(a), "v"(b));
    return d;
}
static __device__ __forceinline__ f32x2 pk_fma(f32x2 a, f32x2 b, f32x2 c) {
    f32x2 d;
    asm("v_pk_fma_f32 %0, %1, %2, %3" : "=v"(d) : "v"(a), "v"(b), "v"(c));
    return d;
}
static __device__ __forceinline__ f32x2 unpack2(unsigned u) {
    f32x2 v;
    v.x = __builtin_bit_cast(float, u << 16);
    v.y = __builtin_bit_cast(float, u & 0xFFFF0000u);
    return v;
}
static __device__ __forceinline__ void gload_lds16(const void* g, void* l) {
    __builtin_amdgcn_global_load_lds((const __attribute__((address_space(1))) unsigned int*)g,
                                     (__attribute__((address_space(3))) unsigned int*)l, 16, 0, 0);
}
static __device__ __forceinline__ int swz(int u) {
    return (((u & 7) ^ ((u >> 3) & 7)) << 3);
}

// ---------------------------------------------------------------- zero halo rings only
__global__ void k_zero_ring(unsigned short* h1h, unsigned short* h2h, unsigned short* xth) {
    int blk = blockIdx.x;
    int img = blk / 260;
    int rp = blk - img * 260;
    int buf = img >> 2, b = img & 3;
    int y, x;
    if (rp < 66) { y = 0; x = rp; }
    else if (rp < 132) { y = 65; x = rp - 66; }
    else { int s2 = rp - 132; y = 1 + (s2 >> 1); x = (s2 & 1) * 65; }
    unsigned short* base = (buf == 0) ? h1h : (buf == 1) ? h2h : xth;
    unsigned* p = (unsigned*)(base + ((size_t)b * HPIX + y * HH + x) * 256);
    p[threadIdx.x] = 0;
}

// ---------------------------------------------------------------- prod
__global__ void k_prod(const float* __restrict__ xn, const float* __restrict__ xr,
                       float* __restrict__ prod) {
    __shared__ float red[4][64];
    int px0 = blockIdx.x * 64;
    int b = px0 >> 12;
    int pxl = threadIdx.x & 63, cg = threadIdx.x >> 6;
    size_t base = (size_t)b * 256 * HWp + (px0 & 4095) + pxl;
    const float* a = xn + base;
    const float* r = xr + base;
    float s = 0.f;
#pragma unroll 8
    for (int c = cg * 64; c < cg * 64 + 64; ++c)
        s += a[(size_t)c * HWp] * r[(size_t)c * HWp];
    red[cg][pxl] = s;
    __syncthreads();
    if (cg == 0)
        prod[px0 + pxl] = red[0][pxl] + red[1][pxl] + red[2][pxl] + red[3][pxl];
}

// ---------------------------------------------------------------- corr
__global__ void k_corr(const float* __restrict__ prod, float* __restrict__ corr) {
    int p = blockIdx.x * blockDim.x + threadIdx.x;
    if (p >= NPIX) return;
    int b = p >> 12, yx = p & 4095, y = yx >> 6, x = yx & 63;
    float s = 0.f;
    for (int dy = -1; dy <= 1; ++dy) {
        int yy = y + dy;
        if (yy < 0 || yy >= Hh) continue;
        for (int dx = -1; dx <= 1; ++dx) {
            int xx = x + dx;
            if (xx < 0 || xx >= Wwd) continue;
            s += prod[b * HWp + yy * Wwd + xx];
        }
    }
    s *= (1.0f / 256.0f);
    corr[p] = (s > 0.f) ? s : 0.1f * s;
}

// ---------------------------------------------------------------- conv1 (Cin=1) -> h1h NHWC halo bf16
__global__ __launch_bounds__(256) void k_conv1(const float* __restrict__ corr,
                                               const float* __restrict__ w1,
                                               const float* __restrict__ b1,
                                               unsigned short* __restrict__ h1h) {
    __shared__ float pt[3][34];
    int px0 = blockIdx.x * 32;
    int b = px0 >> 12, y = (px0 & 4095) >> 6, x0 = px0 & 63;
    int tid = threadIdx.x;
    if (tid < 102) {
        int i = tid / 34, j = tid - i * 34;
        int yy = y - 1 + i, xx = x0 - 1 + j;
        float v = 0.f;
        if (yy >= 0 && yy < Hh && xx >= 0 && xx < Wwd) v = corr[b * HWp + yy * Wwd + xx];
        pt[i][j] = v;
    }
    float wl[9];
#pragma unroll
    for (int k = 0; k < 9; ++k) wl[k] = w1[tid * 9 + k];
    float bias = b1[tid];
    __syncthreads();
    for (int p = 0; p < 32; ++p) {
        float acc = bias;
#pragma unroll
        for (int ky = 0; ky < 3; ++ky)
#pragma unroll
            for (int kx = 0; kx < 3; ++kx) acc = fmaf(pt[ky][p + kx], wl[ky * 3 + kx], acc);
        acc = fmaxf(acc, 0.f);
        h1h[((size_t)b * HPIX + (y + 1) * HH + (x0 + p + 1)) * 256 + tid] = f2bf(acc);
    }
}

// ---------------------------------------------------------------- x_ref NCHW f32 -> NHWC halo bf16
__global__ void k_xth(const float* __restrict__ in, unsigned short* __restrict__ out) {
    __shared__ float t[32][33];
    int b = blockIdx.z;
    int c0 = blockIdx.y * 32;
    int y = blockIdx.x >> 1, x0 = (blockIdx.x & 1) * 32;
    int tx = threadIdx.x, ty = threadIdx.y;
#pragma unroll
    for (int i = 0; i < 32; i += 8)
        t[ty + i][tx] = in[((size_t)b * 256 + c0 + ty + i) * HWp + y * Wwd + x0 + tx];
    __syncthreads();
#pragma unroll
    for (int i = 0; i < 32; i += 8)
        out[((size_t)b * HPIX + (y + 1) * HH + (x0 + ty + i + 1)) * 256 + c0 + tx] =
            f2bf(t[tx][ty + i]);
}

// ---------------------------------------------------------------- weight pack [O][C][9] -> [o][tap*256+c] (linear, conv3g)
__global__ void k_pack(const float* __restrict__ w, unsigned short* __restrict__ out, int O_in) {
    int i = blockIdx.x * 256 + threadIdx.x;
    int o = i / Kdim;
    int r = i - o * Kdim;
    int k = r >> 8, c = r & 255;
    float v = (o < O_in) ? w[((size_t)o * 256 + c) * 9 + k] : 0.f;
    out[i] = f2bf(v);
}

// ---------------------------------------------------------------- frag-pack [O=256][C][9] -> per-(wave,step,frag) 1KB lines
// idx = ((((otile*36+s)*2+kf)*4+mi)*64+lane)*8+e ; o=otile*64+mi*16+(lane&15); kk=s*64+(kf*4+(lane>>4))*8+e
__global__ void k_packf(const float* __restrict__ w, unsigned short* __restrict__ out) {
    int i = blockIdx.x * 256 + threadIdx.x;          // 589824 total
    int e = i & 7;
    int lane = (i >> 3) & 63;
    int mi = (i >> 9) & 3;
    int kf = (i >> 11) & 1;
    int rest = i >> 12;                               // [0,144)
    int s = rest % 36;
    int otile = rest / 36;
    int o = otile * 64 + mi * 16 + (lane & 15);
    int kk = s * 64 + (kf * 4 + (lane >> 4)) * 8 + e;
    int c = kk & 255, tap = kk >> 8;
    out[i] = f2bf(w[((size_t)o * 256 + c) * 9 + tap]);
}

// ---------------------------------------------------------------- conv2 GEMM: 64px x 256o, W in regs, A reg-staged LDS
__global__ __launch_bounds__(256) void k_conv2g(const unsigned short* __restrict__ h1h,
                                                const unsigned short* __restrict__ wbf,
                                                const float* __restrict__ bias,
                                                unsigned short* __restrict__ h2h) {
    __shared__ short S_s[2][64 * 64];                 // A-tile dbuf, 16 KB
    const int tid = threadIdx.x;
    const int bid = blockIdx.x;
    const int px0 = ((bid & 7) * 32 + (bid >> 3)) * 64;   // XCD-bijective
    const int b = px0 >> 12;
    const unsigned short* hb = h1h + (size_t)b * HPIX * 256;
    const int pxl = tid >> 2;                          // 64 px, 4 thr each
    const int px = px0 + pxl;
    const int y = (px & 4095) >> 6, x = px & 63;
    const int u0 = (tid & 3) * 2;                      // two 16B units u0,u0+1
    const int lane = tid & 63, wv = tid >> 6;
    const unsigned short* wfb = wbf + (size_t)wv * NSTEP * 4096 + lane * 8;
    const unsigned short* abase0 = hb + (size_t)((y + 1) * HH + (x + 1)) * 256 + u0 * 8;

    f32x4 acc[4][4] = {};
    u32x4 wA[8], wB[8];
    float bia[4];
#pragma unroll
    for (int oi = 0; oi < 4; ++oi) bia[oi] = bias[wv * 64 + oi * 16 + (lane & 15)];

    const int wr0 = pxl * 64 + ((u0 ^ (pxl & 7)) << 3);
    const int wr1 = pxl * 64 + (((u0 + 1) ^ (pxl & 7)) << 3);

    auto WLOAD = [&](int s, u32x4 (&wreg)[8]) {
#pragma unroll
        for (int f = 0; f < 8; ++f)
            wreg[f] = *(const u32x4*)(wfb + ((size_t)s * 8 + f) * 512);
    };
    auto ALOAD = [&](int s, u32x4& a0, u32x4& a1) {
        int tap = s >> 2, chunk = s & 3;
        int aoff = ((tap / 3 - 1) * HH + (tap % 3 - 1)) * 256 + chunk * 64;
        a0 = *(const u32x4*)(abase0 + aoff);
        a1 = *(const u32x4*)(abase0 + aoff + 8);
    };

    // prologue: stage step 0
    {
        u32x4 a0, a1;
        ALOAD(0, a0, a1);
        WLOAD(0, wA);
        *(u32x4*)&S_s[0][wr0] = a0;
        *(u32x4*)&S_s[0][wr1] = a1;
        asm volatile("s_waitcnt lgkmcnt(0)" ::: "memory");
    }

    auto ITER = [&](int s, u32x4 (&wcur)[8], u32x4 (&wnxt)[8], short* SBc, short* SBn) {
        __builtin_amdgcn_s_barrier();
        __builtin_amdgcn_sched_barrier(0);
        const bool more = (s + 1 < NSTEP);
        u32x4 a0, a1;
        if (more) {
            ALOAD(s + 1, a0, a1);
            WLOAD(s + 1, wnxt);
        }
        short8v af[4][2];
#pragma unroll
        for (int pi = 0; pi < 4; ++pi) {
            int row = pi * 16 + (lane & 15);
#pragma unroll
            for (int kf = 0; kf < 2; ++kf) {
                int c8 = kf * 4 + (lane >> 4);
                af[pi][kf] = *(const short8v*)&SBc[row * 64 + ((c8 ^ (row & 7)) << 3)];
            }
        }
        __builtin_amdgcn_s_setprio(1);
#pragma unroll
        for (int kf = 0; kf < 2; ++kf)
#pragma unroll
            for (int pi = 0; pi < 4; ++pi)
#pragma unroll
                for (int oi = 0; oi < 4; ++oi)
                    acc[pi][oi] = __builtin_amdgcn_mfma_f32_16x16x32_bf16(
                        af[pi][kf], __builtin_bit_cast(short8v, wcur[kf * 4 + oi]),
                        acc[pi][oi], 0, 0, 0);
        __builtin_amdgcn_s_setprio(0);
        if (more) {
            *(u32x4*)&SBn[wr0] = a0;
            *(u32x4*)&SBn[wr1] = a1;
        }
        asm volatile("s_waitcnt lgkmcnt(0)" ::: "memory");
    };

    for (int s2 = 0; s2 < NSTEP; s2 += 2) {
        ITER(s2, wA, wB, &S_s[0][0], &S_s[1][0]);
        ITER(s2 + 1, wB, wA, &S_s[1][0], &S_s[0][0]);
    }

#pragma unroll
    for (int pi = 0; pi < 4; ++pi) {
#pragma unroll
        for (int j = 0; j < 4; ++j) {
            int p2 = px0 + pi * 16 + (lane >> 4) * 4 + j;
            int yy = (p2 & 4095) >> 6, xx = p2 & 63;
            unsigned short* dst = h2h + ((size_t)b * HPIX + (yy + 1) * HH + (xx + 1)) * 256;
#pragma unroll
            for (int oi = 0; oi < 4; ++oi) {
                int o = wv * 64 + oi * 16 + (lane & 15);
                dst[o] = f2bf(fmaxf(acc[pi][oi][j] + bia[oi], 0.f));
            }
        }
    }
}

// ---------------------------------------------------------------- conv3 GEMM: 64px x 32o, BK=64, dbuf (unchanged)
__global__ __launch_bounds__(256) void k_conv3g(const unsigned short* __restrict__ h2h,
                                                const unsigned short* __restrict__ wb,
                                                const float* __restrict__ bias,
                                                float* __restrict__ offp) {
    __shared__ short A_s[2][64 * 64];
    __shared__ short B_s[2][32 * 64];
    const int tid = threadIdx.x;
    const int px0 = blockIdx.x * 64;
    const int b = px0 >> 12;
    const unsigned short* hb = h2h + (size_t)b * HPIX * 256;

    const unsigned short* abase[2];
#pragma unroll
    for (int i = 0; i < 2; ++i) {
        int u = i * 256 + tid;
        int pxl = u >> 3;
        int pxg = px0 + pxl;
        int y = (pxg & 4095) >> 6, x = pxg & 63;
        abase[i] = hb + (size_t)((y + 1) * HH + (x + 1)) * 256 + swz(u);
    }
    const unsigned short* bbase = wb + (size_t)(tid >> 3) * Kdim + swz(tid);

    const int lane = tid & 63, wv = tid >> 6;
    f32x4 acc[2] = {};

    auto STAGE = [&](int s, int buf) {
        int tap = s >> 2, chunk = s & 3;
        int delta = ((tap / 3 - 1) * HH + (tap % 3 - 1)) * 256 + chunk * 64;
        short* Ab = &A_s[buf][0];
#pragma unroll
        for (int i = 0; i < 2; ++i) gload_lds16(abase[i] + delta, Ab + (i * 256 + tid) * 8);
        gload_lds16(bbase + s * 64, &B_s[buf][tid * 8]);
    };

    STAGE(0, 0);
    __syncthreads();
    for (int s = 0; s < NSTEP; ++s) {
        int cur = s & 1;
        if (s + 1 < NSTEP) STAGE(s + 1, cur ^ 1);
        const short* Ab = &A_s[cur][0];
        const short* Bb = &B_s[cur][0];
        short8v af[2], bf[2][2];
#pragma unroll
        for (int kf = 0; kf < 2; ++kf) {
            int row = wv * 16 + (lane & 15);
            int c8 = kf * 4 + (lane >> 4);
            af[kf] = *(const short8v*)&Ab[row * 64 + ((c8 ^ (row & 7)) << 3)];
        }
#pragma unroll
        for (int ni = 0; ni < 2; ++ni) {
            int row = ni * 16 + (lane & 15);
#pragma unroll
            for (int kf = 0; kf < 2; ++kf) {
                int c8 = kf * 4 + (lane >> 4);
                bf[ni][kf] = *(const short8v*)&Bb[row * 64 + ((c8 ^ (row & 7)) << 3)];
            }
        }
#pragma unroll
        for (int kf = 0; kf < 2; ++kf)
#pragma unroll
            for (int ni = 0; ni < 2; ++ni)
                acc[ni] = __builtin_amdgcn_mfma_f32_16x16x32_bf16(af[kf], bf[ni][kf], acc[ni], 0, 0, 0);
        __syncthreads();
    }
#pragma unroll
    for (int j = 0; j < 4; ++j) {
        int px = px0 + wv * 16 + (lane >> 4) * 4 + j;
#pragma unroll
        for (int ni = 0; ni < 2; ++ni) {
            int o = ni * 16 + (lane & 15);
            float bv = (o < 18) ? bias[o] : 0.f;
            offp[(size_t)px * 32 + o] = fmaxf(acc[ni][j] + bv, 0.f);
        }
    }
}

// ---------------------------------------------------------------- dcn GEMM: 64px x 256o, W in regs, fused bilinear
__global__ __launch_bounds__(256) void k_dcng(const unsigned short* __restrict__ xth,
                                              const float* __restrict__ offp,
                                              const unsigned short* __restrict__ wbf,
                                              const float* __restrict__ xn,
                                              float* __restrict__ out) {
    __shared__ short S_s[2][64 * 64];                 // sample dbuf, 16 KB
    const int tid = threadIdx.x;
    const int bid = blockIdx.x;
    const int px0 = ((bid & 7) * 32 + (bid >> 3)) * 64;   // XCD-bijective
    const int b = px0 >> 12;
    const unsigned short* xb = xth + (size_t)b * HPIX * 256;
    const int pxl = tid >> 2;
    const int px = px0 + pxl;
    const int y = (px & 4095) >> 6, x = px & 63;
    const int u0 = (tid & 3) * 2;
    const int lane = tid & 63, wv = tid >> 6;
    const unsigned short* wfb = wbf + (size_t)wv * NSTEP * 4096 + lane * 8;
    const float2* offv = (const float2*)offp;

    f32x4 acc[4][4] = {};
    u32x4 wA[8], wB[8];

    const int wr0 = pxl * 64 + ((u0 ^ (pxl & 7)) << 3);
    const int wr1 = pxl * 64 + (((u0 + 1) ^ (pxl & 7)) << 3);

    const unsigned short* pcorner[4];
    f32x2 wpair[4];
    float2 offn;

    auto SETUP = [&](int tap, float dyo, float dxo) {
        int ky = tap / 3 - 1, kx = tap % 3 - 1;
        float ypos = (float)(y + ky) + dyo;
        float xpos = (float)(x + kx) + dxo;
        float y0f = floorf(ypos), x0f = floorf(xpos);
        float wy = ypos - y0f, wx = xpos - x0f;
        int y0 = (int)y0f, x0 = (int)x0f;
        bool y0v = (y0 >= 0) && (y0 < Hh), y1v = (y0 + 1 >= 0) && (y0 + 1 < Hh);
        bool x0v = (x0 >= 0) && (x0 < Wwd), x1v = (x0 + 1 >= 0) && (x0 + 1 < Wwd);
        int hy0 = min(max(y0, -1), 64) + 1, hy1 = min(max(y0 + 1, -1), 64) + 1;
        int hx0 = min(max(x0, -1), 64) + 1, hx1 = min(max(x0 + 1, -1), 64) + 1;
        float w0 = (1.f - wy) * (1.f - wx) * (float)(y0v && x0v);
        float w1 = (1.f - wy) * wx * (float)(y0v && x1v);
        float w2 = wy * (1.f - wx) * (float)(y1v && x0v);
        float w3 = wy * wx * (float)(y1v && x1v);
        wpair[0] = (f32x2){w0, w0};
        wpair[1] = (f32x2){w1, w1};
        wpair[2] = (f32x2){w2, w2};
        wpair[3] = (f32x2){w3, w3};
        pcorner[0] = xb + (size_t)((hy0 * HH + hx0) * 256) + u0 * 8;
        pcorner[1] = xb + (size_t)((hy0 * HH + hx1) * 256) + u0 * 8;
        pcorner[2] = xb + (size_t)((hy1 * HH + hx0) * 256) + u0 * 8;
        pcorner[3] = xb + (size_t)((hy1 * HH + hx1) * 256) + u0 * 8;
    };
    auto WLOAD = [&](int s, u32x4 (&wreg)[8]) {
#pragma unroll
        for (int f = 0; f < 8; ++f)
            wreg[f] = *(const u32x4*)(wfb + ((size_t)s * 8 + f) * 512);
    };

    // prologue: stage step 0
    {
        float2 o0 = offv[(size_t)px * 16];
        SETUP(0, o0.x, o0.y);
        u32x4 g[4][2];
#pragma unroll
        for (int c = 0; c < 4; ++c) {
            g[c][0] = *(const u32x4*)(pcorner[c]);
            g[c][1] = *(const u32x4*)(pcorner[c] + 8);
        }
        WLOAD(0, wA);
#pragma unroll
        for (int i = 0; i < 2; ++i) {
            u32x4 res;
#pragma unroll
            for (int qd = 0; qd < 4; ++qd) {
                f32x2 a = pk_mul(unpack2(g[0][i][qd]), wpair[0]);
                a = pk_fma(unpack2(g[1][i][qd]), wpair[1], a);
                a = pk_fma(unpack2(g[2][i][qd]), wpair[2], a);
                a = pk_fma(unpack2(g[3][i][qd]), wpair[3], a);
                res[qd] = cvt_pk_bf16(a.x, a.y);
            }
            *(u32x4*)&S_s[0][i == 0 ? wr0 : wr1] = res;
        }
        asm volatile("s_waitcnt lgkmcnt(0)" ::: "memory");
    }

    auto ITER = [&](int s, u32x4 (&wcur)[8], u32x4 (&wnxt)[8], short* SBc, short* SBn) {
        __builtin_amdgcn_s_barrier();
        __builtin_amdgcn_sched_barrier(0);
        const bool more = (s + 1 < NSTEP);
        if ((s & 3) == 0 && (s >> 2) + 1 < 9)
            offn = offv[(size_t)px * 16 + (s >> 2) + 1];
        if (more && ((s + 1) & 3) == 0)
            SETUP((s + 1) >> 2, offn.x, offn.y);
        u32x4 g[4][2];
        if (more) {
            const int nco = ((s + 1) & 3) * 64;
#pragma unroll
            for (int c = 0; c < 4; ++c) {
                g[c][0] = *(const u32x4*)(pcorner[c] + nco);
                g[c][1] = *(const u32x4*)(pcorner[c] + nco + 8);
            }
            WLOAD(s + 1, wnxt);
        }
        short8v sf[4][2];
#pragma unroll
        for (int ni = 0; ni < 4; ++ni) {
            int row = ni * 16 + (lane & 15);
#pragma unroll
            for (int kf = 0; kf < 2; ++kf) {
                int c8 = kf * 4 + (lane >> 4);
                sf[ni][kf] = *(const short8v*)&SBc[row * 64 + ((c8 ^ (row & 7)) << 3)];
            }
        }
        __builtin_amdgcn_s_setprio(1);
#pragma unroll
        for (int kf = 0; kf < 2; ++kf)
#pragma unroll
            for (int mi = 0; mi < 4; ++mi)
#pragma unroll
                for (int ni = 0; ni < 4; ++ni)
                    acc[mi][ni] = __builtin_amdgcn_mfma_f32_16x16x32_bf16(
                        __builtin_bit_cast(short8v, wcur[kf * 4 + mi]), sf[ni][kf],
                        acc[mi][ni], 0, 0, 0);
        __builtin_amdgcn_s_setprio(0);
        if (more) {
#pragma unroll
            for (int i = 0; i < 2; ++i) {
                u32x4 res;
#pragma unroll
                for (int qd = 0; qd < 4; ++qd) {
                    f32x2 a = pk_mul(unpack2(g[0][i][qd]), wpair[0]);
                    a = pk_fma(unpack2(g[1][i][qd]), wpair[1], a);
                    a = pk_fma(unpack2(g[2][i][qd]), wpair[2], a);
                    a = pk_fma(unpack2(g[3][i][qd]), wpair[3], a);
                    res[qd] = cvt_pk_bf16(a.x, a.y);
                }
                *(u32x4*)&SBn[i == 0 ? wr0 : wr1] = res;
            }
        }
        asm volatile("s_waitcnt lgkmcnt(0)" ::: "memory");
    };

    for (int s2 = 0; s2 < NSTEP; s2 += 2) {
        ITER(s2, wA, wB, &S_s[0][0], &S_s[1][0]);
        ITER(s2 + 1, wB, wA, &S_s[1][0], &S_s[0][0]);
    }

#pragma unroll
    for (int mi = 0; mi < 4; ++mi) {
        int o = wv * 64 + mi * 16 + (lane >> 4) * 4;
#pragma unroll
        for (int j = 0; j < 4; ++j) {
            size_t rowbase = ((size_t)b * 256 + o + j) * HWp;
#pragma unroll
            for (int ni = 0; ni < 4; ++ni) {
                int p2 = (px0 + ni * 16 + (lane & 15)) & 4095;
                size_t idx = rowbase + p2;
                out[idx] = 0.5f * (xn[idx] + fmaxf(acc[mi][ni][j], 0.f));
            }
        }
    }
}

extern "C" void kernel_launch(void* const* d_in, const int* in_sizes, int n_in,
                              void* d_out, int out_size, void* d_ws, size_t ws_size,
                              hipStream_t stream) {
    const float* x_ref  = (const float*)d_in[0];
    const float* x_next = (const float*)d_in[1];
    const float* w1 = (const float*)d_in[2];
    const float* b1 = (const float*)d_in[3];
    const float* w2 = (const float*)d_in[4];
    const float* b2 = (const float*)d_in[5];
    const float* w3 = (const float*)d_in[6];
    const float* b3 = (const float*)d_in[7];
    const float* wd = (const float*)d_in[8];
    float* out = (float*)d_out;
    char* ws = (char*)d_ws;

    unsigned short* h1h = (unsigned short*)(ws + B_H1H);
    unsigned short* h2h = (unsigned short*)(ws + B_H2H);
    unsigned short* xth = (unsigned short*)(ws + B_XTH);
    float* prod = (float*)(ws + B_PROD);
    float* corr = (float*)(ws + B_CORR);
    float* offp = (float*)(ws + B_OFFP);
    unsigned short* wb2f = (unsigned short*)(ws + B_WB2);
    unsigned short* wbdf = (unsigned short*)(ws + B_WBD);
    unsigned short* wb3  = (unsigned short*)(ws + B_WB3);

    k_zero_ring<<<12 * 260, 128, 0, stream>>>(h1h, h2h, xth);
    k_prod<<<NPIX / 64, 256, 0, stream>>>(x_next, x_ref, prod);
    k_corr<<<NPIX / 256, 256, 0, stream>>>(prod, corr);
    k_conv1<<<NPIX / 32, 256, 0, stream>>>(corr, w1, b1, h1h);
    k_xth<<<dim3(128, 8, Bsz), dim3(32, 8), 0, stream>>>(x_ref, xth);
    k_packf<<<(256 * Kdim) / 256, 256, 0, stream>>>(w2, wb2f);
    k_packf<<<(256 * Kdim) / 256, 256, 0, stream>>>(wd, wbdf);
    k_pack<<<(32 * Kdim) / 256, 256, 0, stream>>>(w3, wb3, 18);
    k_conv2g<<<256, 256, 0, stream>>>(h1h, wb2f, b2, h2h);
    k_conv3g<<<256, 256, 0, stream>>>(h2h, wb3, b3, offp);
    k_dcng<<<256, 256, 0, stream>>>(xth, offp, wbdf, x_next, out);
}

// Round 7
// 127.241 us; speedup vs baseline: 29.4354x; 1.0437x over previous
//
#include <hip/hip_runtime.h>

typedef __attribute__((ext_vector_type(8))) short short8v;
typedef __attribute__((ext_vector_type(4))) float f32x4;
typedef __attribute__((ext_vector_type(2))) float f32x2;
typedef __attribute__((ext_vector_type(4))) unsigned int u32x4;

constexpr int Bsz = 4;
constexpr int Hh = 64, Wwd = 64;
constexpr int HWp = Hh * Wwd;            // 4096
constexpr int NPIX = Bsz * HWp;          // 16384
constexpr int HH = 66;                   // halo dim
constexpr int HPIX = HH * HH;            // 4356
constexpr int Kdim = 2304;               // 9*256
constexpr int NSTEP = 36;                // Kdim / 64

// ---- workspace byte offsets
constexpr size_t B_H1H  = 0;
constexpr size_t HALO_BYTES = (size_t)Bsz * HPIX * 256 * 2;      // 8,921,088
constexpr size_t B_H2H  = B_H1H + HALO_BYTES;
constexpr size_t B_XTH  = B_H2H + HALO_BYTES;
constexpr size_t B_PROD = B_XTH + HALO_BYTES;
constexpr size_t B_CORR = B_PROD + (size_t)NPIX * 4;
constexpr size_t B_OFFP = B_CORR + (size_t)NPIX * 4;
constexpr size_t B_WB2  = B_OFFP + (size_t)NPIX * 32 * 4;        // frag-packed
constexpr size_t B_WBD  = B_WB2 + (size_t)256 * Kdim * 2;        // frag-packed
constexpr size_t B_WB3  = B_WBD + (size_t)256 * Kdim * 2;        // linear (conv3g)

static __device__ __forceinline__ unsigned short f2bf(float f) {
    unsigned u = __builtin_bit_cast(unsigned, f);
    u += 0x7FFFu + ((u >> 16) & 1u);
    return (unsigned short)(u >> 16);
}
static __device__ __forceinline__ unsigned cvt_pk_bf16(float lo, float hi) {
    unsigned r;
    asm("v_cvt_pk_bf16_f32 %0, %1, %2" : "=v"(r) : "v"(lo), "v"(hi));
    return r;
}
static __device__ __forceinline__ f32x2 pk_mul(f32x2 a, f32x2 b) {
    f32x2 d;
    asm("v_pk_mul_f32 %0, %1, %2" : "=v"(d) : "v"(a), "v"(b));
    return d;
}
static __device__ __forceinline__ f32x2 pk_fma(f32x2 a, f32x2 b, f32x2 c) {
    f32x2 d;
    asm("v_pk_fma_f32 %0, %1, %2, %3" : "=v"(d) : "v"(a), "v"(b), "v"(c));
    return d;
}
static __device__ __forceinline__ f32x2 unpack2(unsigned u) {
    f32x2 v;
    v.x = __builtin_bit_cast(float, u << 16);
    v.y = __builtin_bit_cast(float, u & 0xFFFF0000u);
    return v;
}
static __device__ __forceinline__ void gload_lds16(const void* g, void* l) {
    __builtin_amdgcn_global_load_lds((const __attribute__((address_space(1))) unsigned int*)g,
                                     (__attribute__((address_space(3))) unsigned int*)l, 16, 0, 0);
}
static __device__ __forceinline__ int swz(int u) {
    return (((u & 7) ^ ((u >> 3) & 7)) << 3);
}

// ---------------------------------------------------------------- zero halo rings only
__global__ void k_zero_ring(unsigned short* h1h, unsigned short* h2h, unsigned short* xth) {
    int blk = blockIdx.x;
    int img = blk / 260;
    int rp = blk - img * 260;
    int buf = img >> 2, b = img & 3;
    int y, x;
    if (rp < 66) { y = 0; x = rp; }
    else if (rp < 132) { y = 65; x = rp - 66; }
    else { int s2 = rp - 132; y = 1 + (s2 >> 1); x = (s2 & 1) * 65; }
    unsigned short* base = (buf == 0) ? h1h : (buf == 1) ? h2h : xth;
    unsigned* p = (unsigned*)(base + ((size_t)b * HPIX + y * HH + x) * 256);
    p[threadIdx.x] = 0;
}

// ---------------------------------------------------------------- prod
__global__ void k_prod(const float* __restrict__ xn, const float* __restrict__ xr,
                       float* __restrict__ prod) {
    __shared__ float red[4][64];
    int px0 = blockIdx.x * 64;
    int b = px0 >> 12;
    int pxl = threadIdx.x & 63, cg = threadIdx.x >> 6;
    size_t base = (size_t)b * 256 * HWp + (px0 & 4095) + pxl;
    const float* a = xn + base;
    const float* r = xr + base;
    float s = 0.f;
#pragma unroll 8
    for (int c = cg * 64; c < cg * 64 + 64; ++c)
        s += a[(size_t)c * HWp] * r[(size_t)c * HWp];
    red[cg][pxl] = s;
    __syncthreads();
    if (cg == 0)
        prod[px0 + pxl] = red[0][pxl] + red[1][pxl] + red[2][pxl] + red[3][pxl];
}

// ---------------------------------------------------------------- corr
__global__ void k_corr(const float* __restrict__ prod, float* __restrict__ corr) {
    int p = blockIdx.x * blockDim.x + threadIdx.x;
    if (p >= NPIX) return;
    int b = p >> 12, yx = p & 4095, y = yx >> 6, x = yx & 63;
    float s = 0.f;
    for (int dy = -1; dy <= 1; ++dy) {
        int yy = y + dy;
        if (yy < 0 || yy >= Hh) continue;
        for (int dx = -1; dx <= 1; ++dx) {
            int xx = x + dx;
            if (xx < 0 || xx >= Wwd) continue;
            s += prod[b * HWp + yy * Wwd + xx];
        }
    }
    s *= (1.0f / 256.0f);
    corr[p] = (s > 0.f) ? s : 0.1f * s;
}

// ---------------------------------------------------------------- conv1 (Cin=1) -> h1h NHWC halo bf16
__global__ __launch_bounds__(256) void k_conv1(const float* __restrict__ corr,
                                               const float* __restrict__ w1,
                                               const float* __restrict__ b1,
                                               unsigned short* __restrict__ h1h) {
    __shared__ float pt[3][34];
    int px0 = blockIdx.x * 32;
    int b = px0 >> 12, y = (px0 & 4095) >> 6, x0 = px0 & 63;
    int tid = threadIdx.x;
    if (tid < 102) {
        int i = tid / 34, j = tid - i * 34;
        int yy = y - 1 + i, xx = x0 - 1 + j;
        float v = 0.f;
        if (yy >= 0 && yy < Hh && xx >= 0 && xx < Wwd) v = corr[b * HWp + yy * Wwd + xx];
        pt[i][j] = v;
    }
    float wl[9];
#pragma unroll
    for (int k = 0; k < 9; ++k) wl[k] = w1[tid * 9 + k];
    float bias = b1[tid];
    __syncthreads();
    for (int p = 0; p < 32; ++p) {
        float acc = bias;
#pragma unroll
        for (int ky = 0; ky < 3; ++ky)
#pragma unroll
            for (int kx = 0; kx < 3; ++kx) acc = fmaf(pt[ky][p + kx], wl[ky * 3 + kx], acc);
        acc = fmaxf(acc, 0.f);
        h1h[((size_t)b * HPIX + (y + 1) * HH + (x0 + p + 1)) * 256 + tid] = f2bf(acc);
    }
}

// ---------------------------------------------------------------- x_ref NCHW f32 -> NHWC halo bf16
__global__ void k_xth(const float* __restrict__ in, unsigned short* __restrict__ out) {
    __shared__ float t[32][33];
    int b = blockIdx.z;
    int c0 = blockIdx.y * 32;
    int y = blockIdx.x >> 1, x0 = (blockIdx.x & 1) * 32;
    int tx = threadIdx.x, ty = threadIdx.y;
#pragma unroll
    for (int i = 0; i < 32; i += 8)
        t[ty + i][tx] = in[((size_t)b * 256 + c0 + ty + i) * HWp + y * Wwd + x0 + tx];
    __syncthreads();
#pragma unroll
    for (int i = 0; i < 32; i += 8)
        out[((size_t)b * HPIX + (y + 1) * HH + (x0 + ty + i + 1)) * 256 + c0 + tx] =
            f2bf(t[tx][ty + i]);
}

// ---------------------------------------------------------------- weight pack (linear, conv3g)
__global__ void k_pack(const float* __restrict__ w, unsigned short* __restrict__ out, int O_in) {
    int i = blockIdx.x * 256 + threadIdx.x;
    int o = i / Kdim;
    int r = i - o * Kdim;
    int k = r >> 8, c = r & 255;
    float v = (o < O_in) ? w[((size_t)o * 256 + c) * 9 + k] : 0.f;
    out[i] = f2bf(v);
}

// ---------------------------------------------------------------- frag-pack for 8-wave 32o tiles
// idx = ((((wv*36+s)*2+kf)*2+mi)*64+lane)*8+e ; o=wv*32+mi*16+(lane&15); kk=s*64+(kf*4+(lane>>4))*8+e
__global__ void k_packf(const float* __restrict__ w, unsigned short* __restrict__ out) {
    int i = blockIdx.x * 256 + threadIdx.x;          // 589824 total
    int e = i & 7;
    int lane = (i >> 3) & 63;
    int mi = (i >> 9) & 1;
    int kf = (i >> 10) & 1;
    int rest = i >> 11;                               // [0,288)
    int s = rest % 36;
    int wv = rest / 36;
    int o = wv * 32 + mi * 16 + (lane & 15);
    int kk = s * 64 + (kf * 4 + (lane >> 4)) * 8 + e;
    int c = kk & 255, tap = kk >> 8;
    out[i] = f2bf(w[((size_t)o * 256 + c) * 9 + tap]);
}

// ---------------------------------------------------------------- conv2 GEMM: 64px x 256o, 8 waves, W in regs
__global__ __launch_bounds__(512) void k_conv2g(const unsigned short* __restrict__ h1h,
                                                const unsigned short* __restrict__ wbf,
                                                const float* __restrict__ bias,
                                                unsigned short* __restrict__ h2h) {
    __shared__ short S_s[2][64 * 64];                 // A-tile dbuf, 16 KB
    const int tid = threadIdx.x;
    const int bid = blockIdx.x;
    const int px0 = ((bid & 7) * 32 + (bid >> 3)) * 64;   // XCD-bijective
    const int b = px0 >> 12;
    const unsigned short* hb = h1h + (size_t)b * HPIX * 256;
    const int pxl = tid >> 3;                          // 64 px, 8 thr each
    const int px = px0 + pxl;
    const int y = (px & 4095) >> 6, x = px & 63;
    const int u0 = tid & 7;                            // one 16B unit
    const int lane = tid & 63, wv = tid >> 6;          // 8 waves x 32o
    const unsigned short* wfb = wbf + (size_t)wv * NSTEP * 2048 + lane * 8;
    const unsigned short* abase0 = hb + (size_t)((y + 1) * HH + (x + 1)) * 256 + u0 * 8;

    f32x4 acc[4][2] = {};
    u32x4 wA[4], wB[4];
    float bia[2];
#pragma unroll
    for (int oi = 0; oi < 2; ++oi) bia[oi] = bias[wv * 32 + oi * 16 + (lane & 15)];

    const int wr0 = pxl * 64 + ((u0 ^ (pxl & 7)) << 3);

    auto WLOAD = [&](int s, u32x4 (&wreg)[4]) {
#pragma unroll
        for (int f = 0; f < 4; ++f)
            wreg[f] = *(const u32x4*)(wfb + ((size_t)s * 4 + f) * 512);
    };
    auto ALOAD = [&](int s) {
        int tap = s >> 2, chunk = s & 3;
        int aoff = ((tap / 3 - 1) * HH + (tap % 3 - 1)) * 256 + chunk * 64;
        return *(const u32x4*)(abase0 + aoff);
    };

    // prologue
    {
        u32x4 a0 = ALOAD(0);
        WLOAD(0, wA);
        *(u32x4*)&S_s[0][wr0] = a0;
        asm volatile("s_waitcnt lgkmcnt(0)" ::: "memory");
    }

    auto ITER = [&](int s, u32x4 (&wcur)[4], u32x4 (&wnxt)[4], short* SBc, short* SBn) {
        __builtin_amdgcn_s_barrier();
        __builtin_amdgcn_sched_barrier(0);
        const bool more = (s + 1 < NSTEP);
        u32x4 a0;
        if (more) {
            a0 = ALOAD(s + 1);
            WLOAD(s + 1, wnxt);
        }
        short8v af[4][2];
#pragma unroll
        for (int pi = 0; pi < 4; ++pi) {
            int row = pi * 16 + (lane & 15);
#pragma unroll
            for (int kf = 0; kf < 2; ++kf) {
                int c8 = kf * 4 + (lane >> 4);
                af[pi][kf] = *(const short8v*)&SBc[row * 64 + ((c8 ^ (row & 7)) << 3)];
            }
        }
        __builtin_amdgcn_s_setprio(1);
#pragma unroll
        for (int kf = 0; kf < 2; ++kf)
#pragma unroll
            for (int pi = 0; pi < 4; ++pi)
#pragma unroll
                for (int oi = 0; oi < 2; ++oi)
                    acc[pi][oi] = __builtin_amdgcn_mfma_f32_16x16x32_bf16(
                        af[pi][kf], __builtin_bit_cast(short8v, wcur[kf * 2 + oi]),
                        acc[pi][oi], 0, 0, 0);
        __builtin_amdgcn_s_setprio(0);
        if (more) *(u32x4*)&SBn[wr0] = a0;
        asm volatile("s_waitcnt lgkmcnt(0)" ::: "memory");
    };

    for (int s2 = 0; s2 < NSTEP; s2 += 2) {
        ITER(s2, wA, wB, &S_s[0][0], &S_s[1][0]);
        ITER(s2 + 1, wB, wA, &S_s[1][0], &S_s[0][0]);
    }

#pragma unroll
    for (int pi = 0; pi < 4; ++pi) {
#pragma unroll
        for (int j = 0; j < 4; ++j) {
            int p2 = px0 + pi * 16 + (lane >> 4) * 4 + j;
            int yy = (p2 & 4095) >> 6, xx = p2 & 63;
            unsigned short* dst = h2h + ((size_t)b * HPIX + (yy + 1) * HH + (xx + 1)) * 256;
#pragma unroll
            for (int oi = 0; oi < 2; ++oi) {
                int o = wv * 32 + oi * 16 + (lane & 15);
                dst[o] = f2bf(fmaxf(acc[pi][oi][j] + bia[oi], 0.f));
            }
        }
    }
}

// ---------------------------------------------------------------- conv3 GEMM: 64px x 32o, BK=64, dbuf (unchanged)
__global__ __launch_bounds__(256) void k_conv3g(const unsigned short* __restrict__ h2h,
                                                const unsigned short* __restrict__ wb,
                                                const float* __restrict__ bias,
                                                float* __restrict__ offp) {
    __shared__ short A_s[2][64 * 64];
    __shared__ short B_s[2][32 * 64];
    const int tid = threadIdx.x;
    const int px0 = blockIdx.x * 64;
    const int b = px0 >> 12;
    const unsigned short* hb = h2h + (size_t)b * HPIX * 256;

    const unsigned short* abase[2];
#pragma unroll
    for (int i = 0; i < 2; ++i) {
        int u = i * 256 + tid;
        int pxl = u >> 3;
        int pxg = px0 + pxl;
        int y = (pxg & 4095) >> 6, x = pxg & 63;
        abase[i] = hb + (size_t)((y + 1) * HH + (x + 1)) * 256 + swz(u);
    }
    const unsigned short* bbase = wb + (size_t)(tid >> 3) * Kdim + swz(tid);

    const int lane = tid & 63, wv = tid >> 6;
    f32x4 acc[2] = {};

    auto STAGE = [&](int s, int buf) {
        int tap = s >> 2, chunk = s & 3;
        int delta = ((tap / 3 - 1) * HH + (tap % 3 - 1)) * 256 + chunk * 64;
        short* Ab = &A_s[buf][0];
#pragma unroll
        for (int i = 0; i < 2; ++i) gload_lds16(abase[i] + delta, Ab + (i * 256 + tid) * 8);
        gload_lds16(bbase + s * 64, &B_s[buf][tid * 8]);
    };

    STAGE(0, 0);
    __syncthreads();
    for (int s = 0; s < NSTEP; ++s) {
        int cur = s & 1;
        if (s + 1 < NSTEP) STAGE(s + 1, cur ^ 1);
        const short* Ab = &A_s[cur][0];
        const short* Bb = &B_s[cur][0];
        short8v af[2], bf[2][2];
#pragma unroll
        for (int kf = 0; kf < 2; ++kf) {
            int row = wv * 16 + (lane & 15);
            int c8 = kf * 4 + (lane >> 4);
            af[kf] = *(const short8v*)&Ab[row * 64 + ((c8 ^ (row & 7)) << 3)];
        }
#pragma unroll
        for (int ni = 0; ni < 2; ++ni) {
            int row = ni * 16 + (lane & 15);
#pragma unroll
            for (int kf = 0; kf < 2; ++kf) {
                int c8 = kf * 4 + (lane >> 4);
                bf[ni][kf] = *(const short8v*)&Bb[row * 64 + ((c8 ^ (row & 7)) << 3)];
            }
        }
#pragma unroll
        for (int kf = 0; kf < 2; ++kf)
#pragma unroll
            for (int ni = 0; ni < 2; ++ni)
                acc[ni] = __builtin_amdgcn_mfma_f32_16x16x32_bf16(af[kf], bf[ni][kf], acc[ni], 0, 0, 0);
        __syncthreads();
    }
#pragma unroll
    for (int j = 0; j < 4; ++j) {
        int px = px0 + wv * 16 + (lane >> 4) * 4 + j;
#pragma unroll
        for (int ni = 0; ni < 2; ++ni) {
            int o = ni * 16 + (lane & 15);
            float bv = (o < 18) ? bias[o] : 0.f;
            offp[(size_t)px * 32 + o] = fmaxf(acc[ni][j] + bv, 0.f);
        }
    }
}

// ---------------------------------------------------------------- dcn GEMM: 64px x 256o, 8 waves, W in regs, fused bilinear
__global__ __launch_bounds__(512) void k_dcng(const unsigned short* __restrict__ xth,
                                              const float* __restrict__ offp,
                                              const unsigned short* __restrict__ wbf,
                                              const float* __restrict__ xn,
                                              float* __restrict__ out) {
    __shared__ short S_s[2][64 * 64];                 // sample dbuf, 16 KB
    const int tid = threadIdx.x;
    const int bid = blockIdx.x;
    const int px0 = ((bid & 7) * 32 + (bid >> 3)) * 64;   // XCD-bijective
    const int b = px0 >> 12;
    const unsigned short* xb = xth + (size_t)b * HPIX * 256;
    const int pxl = tid >> 3;                          // 64 px, 8 thr each
    const int px = px0 + pxl;
    const int y = (px & 4095) >> 6, x = px & 63;
    const int u0 = tid & 7;                            // one 16B unit
    const int lane = tid & 63, wv = tid >> 6;          // 8 waves x 32o
    const unsigned short* wfb = wbf + (size_t)wv * NSTEP * 2048 + lane * 8;
    const float2* offv = (const float2*)offp;

    f32x4 acc[2][4] = {};
    u32x4 wA[4], wB[4];
    const int wr0 = pxl * 64 + ((u0 ^ (pxl & 7)) << 3);

    const unsigned short* pcorner[4];
    f32x2 wpair[4];
    float2 offn;

    auto SETUP = [&](int tap, float dyo, float dxo) {
        int ky = tap / 3 - 1, kx = tap % 3 - 1;
        float ypos = (float)(y + ky) + dyo;
        float xpos = (float)(x + kx) + dxo;
        float y0f = floorf(ypos), x0f = floorf(xpos);
        float wy = ypos - y0f, wx = xpos - x0f;
        int y0 = (int)y0f, x0 = (int)x0f;
        bool y0v = (y0 >= 0) && (y0 < Hh), y1v = (y0 + 1 >= 0) && (y0 + 1 < Hh);
        bool x0v = (x0 >= 0) && (x0 < Wwd), x1v = (x0 + 1 >= 0) && (x0 + 1 < Wwd);
        int hy0 = min(max(y0, -1), 64) + 1, hy1 = min(max(y0 + 1, -1), 64) + 1;
        int hx0 = min(max(x0, -1), 64) + 1, hx1 = min(max(x0 + 1, -1), 64) + 1;
        float w0 = (1.f - wy) * (1.f - wx) * (float)(y0v && x0v);
        float w1 = (1.f - wy) * wx * (float)(y0v && x1v);
        float w2 = wy * (1.f - wx) * (float)(y1v && x0v);
        float w3 = wy * wx * (float)(y1v && x1v);
        wpair[0] = (f32x2){w0, w0};
        wpair[1] = (f32x2){w1, w1};
        wpair[2] = (f32x2){w2, w2};
        wpair[3] = (f32x2){w3, w3};
        pcorner[0] = xb + (size_t)((hy0 * HH + hx0) * 256) + u0 * 8;
        pcorner[1] = xb + (size_t)((hy0 * HH + hx1) * 256) + u0 * 8;
        pcorner[2] = xb + (size_t)((hy1 * HH + hx0) * 256) + u0 * 8;
        pcorner[3] = xb + (size_t)((hy1 * HH + hx1) * 256) + u0 * 8;
    };
    auto WLOAD = [&](int s, u32x4 (&wreg)[4]) {
#pragma unroll
        for (int f = 0; f < 4; ++f)
            wreg[f] = *(const u32x4*)(wfb + ((size_t)s * 4 + f) * 512);
    };

    // prologue: stage step 0
    {
        float2 o0 = offv[(size_t)px * 16];
        SETUP(0, o0.x, o0.y);
        u32x4 g[4];
#pragma unroll
        for (int c = 0; c < 4; ++c) g[c] = *(const u32x4*)(pcorner[c]);
        WLOAD(0, wA);
        u32x4 res;
#pragma unroll
        for (int qd = 0; qd < 4; ++qd) {
            f32x2 a = pk_mul(unpack2(g[0][qd]), wpair[0]);
            a = pk_fma(unpack2(g[1][qd]), wpair[1], a);
            a = pk_fma(unpack2(g[2][qd]), wpair[2], a);
            a = pk_fma(unpack2(g[3][qd]), wpair[3], a);
            res[qd] = cvt_pk_bf16(a.x, a.y);
        }
        *(u32x4*)&S_s[0][wr0] = res;
        asm volatile("s_waitcnt lgkmcnt(0)" ::: "memory");
    }

    auto ITER = [&](int s, u32x4 (&wcur)[4], u32x4 (&wnxt)[4], short* SBc, short* SBn) {
        __builtin_amdgcn_s_barrier();
        __builtin_amdgcn_sched_barrier(0);
        const bool more = (s + 1 < NSTEP);
        if ((s & 3) == 0 && (s >> 2) + 1 < 9)
            offn = offv[(size_t)px * 16 + (s >> 2) + 1];
        if (more && ((s + 1) & 3) == 0)
            SETUP((s + 1) >> 2, offn.x, offn.y);
        u32x4 g[4];
        if (more) {
            const int nco = ((s + 1) & 3) * 64;
#pragma unroll
            for (int c = 0; c < 4; ++c) g[c] = *(const u32x4*)(pcorner[c] + nco);
            WLOAD(s + 1, wnxt);
        }
        short8v sf[4][2];
#pragma unroll
        for (int ni = 0; ni < 4; ++ni) {
            int row = ni * 16 + (lane & 15);
#pragma unroll
            for (int kf = 0; kf < 2; ++kf) {
                int c8 = kf * 4 + (lane >> 4);
                sf[ni][kf] = *(const short8v*)&SBc[row * 64 + ((c8 ^ (row & 7)) << 3)];
            }
        }
        __builtin_amdgcn_s_setprio(1);
#pragma unroll
        for (int kf = 0; kf < 2; ++kf)
#pragma unroll
            for (int mi = 0; mi < 2; ++mi)
#pragma unroll
                for (int ni = 0; ni < 4; ++ni)
                    acc[mi][ni] = __builtin_amdgcn_mfma_f32_16x16x32_bf16(
                        __builtin_bit_cast(short8v, wcur[kf * 2 + mi]), sf[ni][kf],
                        acc[mi][ni], 0, 0, 0);
        __builtin_amdgcn_s_setprio(0);
        if (more) {
            u32x4 res;
#pragma unroll
            for (int qd = 0; qd < 4; ++qd) {
                f32x2 a = pk_mul(unpack2(g[0][qd]), wpair[0]);
                a = pk_fma(unpack2(g[1][qd]), wpair[1], a);
                a = pk_fma(unpack2(g[2][qd]), wpair[2], a);
                a = pk_fma(unpack2(g[3][qd]), wpair[3], a);
                res[qd] = cvt_pk_bf16(a.x, a.y);
            }
            *(u32x4*)&SBn[wr0] = res;
        }
        asm volatile("s_waitcnt lgkmcnt(0)" ::: "memory");
    };

    for (int s2 = 0; s2 < NSTEP; s2 += 2) {
        ITER(s2, wA, wB, &S_s[0][0], &S_s[1][0]);
        ITER(s2 + 1, wB, wA, &S_s[1][0], &S_s[0][0]);
    }

#pragma unroll
    for (int mi = 0; mi < 2; ++mi) {
        int o = wv * 32 + mi * 16 + (lane >> 4) * 4;
#pragma unroll
        for (int j = 0; j < 4; ++j) {
            size_t rowbase = ((size_t)b * 256 + o + j) * HWp;
#pragma unroll
            for (int ni = 0; ni < 4; ++ni) {
                int p2 = (px0 + ni * 16 + (lane & 15)) & 4095;
                size_t idx = rowbase + p2;
                out[idx] = 0.5f * (xn[idx] + fmaxf(acc[mi][ni][j], 0.f));
            }
        }
    }
}

extern "C" void kernel_launch(void* const* d_in, const int* in_sizes, int n_in,
                              void* d_out, int out_size, void* d_ws, size_t ws_size,
                              hipStream_t stream) {
    const float* x_ref  = (const float*)d_in[0];
    const float* x_next = (const float*)d_in[1];
    const float* w1 = (const float*)d_in[2];
    const float* b1 = (const float*)d_in[3];
    const float* w2 = (const float*)d_in[4];
    const float* b2 = (const float*)d_in[5];
    const float* w3 = (const float*)d_in[6];
    const float* b3 = (const float*)d_in[7];
    const float* wd = (const float*)d_in[8];
    float* out = (float*)d_out;
    char* ws = (char*)d_ws;

    unsigned short* h1h = (unsigned short*)(ws + B_H1H);
    unsigned short* h2h = (unsigned short*)(ws + B_H2H);
    unsigned short* xth = (unsigned short*)(ws + B_XTH);
    float* prod = (float*)(ws + B_PROD);
    float* corr = (float*)(ws + B_CORR);
    float* offp = (float*)(ws + B_OFFP);
    unsigned short* wb2f = (unsigned short*)(ws + B_WB2);
    unsigned short* wbdf = (unsigned short*)(ws + B_WBD);
    unsigned short* wb3  = (unsigned short*)(ws + B_WB3);

    k_zero_ring<<<12 * 260, 128, 0, stream>>>(h1h, h2h, xth);
    k_prod<<<NPIX / 64, 256, 0, stream>>>(x_next, x_ref, prod);
    k_corr<<<NPIX / 256, 256, 0, stream>>>(prod, corr);
    k_conv1<<<NPIX / 32, 256, 0, stream>>>(corr, w1, b1, h1h);
    k_xth<<<dim3(128, 8, Bsz), dim3(32, 8), 0, stream>>>(x_ref, xth);
    k_packf<<<(256 * Kdim) / 256, 256, 0, stream>>>(w2, wb2f);
    k_packf<<<(256 * Kdim) / 256, 256, 0, stream>>>(wd, wbdf);
    k_pack<<<(32 * Kdim) / 256, 256, 0, stream>>>(w3, wb3, 18);
    k_conv2g<<<256, 512, 0, stream>>>(h1h, wb2f, b2, h2h);
    k_conv3g<<<256, 256, 0, stream>>>(h2h, wb3, b3, offp);
    k_dcng<<<256, 512, 0, stream>>>(xth, offp, wbdf, x_next, out);
}

// Round 8
// 121.410 us; speedup vs baseline: 30.8490x; 1.0480x over previous
//
#include <hip/hip_runtime.h>

typedef __attribute__((ext_vector_type(8))) short short8v;
typedef __attribute__((ext_vector_type(4))) float f32x4;
typedef __attribute__((ext_vector_type(2))) float f32x2;
typedef __attribute__((ext_vector_type(4))) unsigned int u32x4;

constexpr int Bsz = 4;
constexpr int Hh = 64, Wwd = 64;
constexpr int HWp = Hh * Wwd;            // 4096
constexpr int NPIX = Bsz * HWp;          // 16384
constexpr int HH = 66;                   // halo dim
constexpr int HPIX = HH * HH;            // 4356
constexpr int Kdim = 2304;               // 9*256
constexpr int NSTEP = 36;                // Kdim / 64

// ---- workspace byte offsets
constexpr size_t B_H1H  = 0;
constexpr size_t HALO_BYTES = (size_t)Bsz * HPIX * 256 * 2;      // 8,921,088
constexpr size_t B_H2H  = B_H1H + HALO_BYTES;
constexpr size_t B_XTH  = B_H2H + HALO_BYTES;
constexpr size_t B_PROD = B_XTH + HALO_BYTES;
constexpr size_t B_CORR = B_PROD + (size_t)NPIX * 4;
constexpr size_t B_OFFP = B_CORR + (size_t)NPIX * 4;
constexpr size_t B_WB2  = B_OFFP + (size_t)NPIX * 32 * 4;        // frag-packed
constexpr size_t B_WBD  = B_WB2 + (size_t)256 * Kdim * 2;        // frag-packed
constexpr size_t B_WB3  = B_WBD + (size_t)256 * Kdim * 2;        // linear (conv3g)

static __device__ __forceinline__ unsigned short f2bf(float f) {
    unsigned u = __builtin_bit_cast(unsigned, f);
    u += 0x7FFFu + ((u >> 16) & 1u);
    return (unsigned short)(u >> 16);
}
static __device__ __forceinline__ unsigned cvt_pk_bf16(float lo, float hi) {
    unsigned r;
    asm("v_cvt_pk_bf16_f32 %0, %1, %2" : "=v"(r) : "v"(lo), "v"(hi));
    return r;
}
static __device__ __forceinline__ f32x2 pk_mul(f32x2 a, f32x2 b) {
    f32x2 d;
    asm("v_pk_mul_f32 %0, %1, %2" : "=v"(d) : "v"(a), "v"(b));
    return d;
}
static __device__ __forceinline__ f32x2 pk_fma(f32x2 a, f32x2 b, f32x2 c) {
    f32x2 d;
    asm("v_pk_fma_f32 %0, %1, %2, %3" : "=v"(d) : "v"(a), "v"(b), "v"(c));
    return d;
}
static __device__ __forceinline__ f32x2 unpack2(unsigned u) {
    f32x2 v;
    v.x = __builtin_bit_cast(float, u << 16);
    v.y = __builtin_bit_cast(float, u & 0xFFFF0000u);
    return v;
}
static __device__ __forceinline__ void gload_lds16(const void* g, void* l) {
    __builtin_amdgcn_global_load_lds((const __attribute__((address_space(1))) unsigned int*)g,
                                     (__attribute__((address_space(3))) unsigned int*)l, 16, 0, 0);
}
static __device__ __forceinline__ int swz(int u) {
    return (((u & 7) ^ ((u >> 3) & 7)) << 3);
}

// ---------------------------------------------------------------- zero halo rings only
__global__ void k_zero_ring(unsigned short* h1h, unsigned short* h2h, unsigned short* xth) {
    int blk = blockIdx.x;
    int img = blk / 260;
    int rp = blk - img * 260;
    int buf = img >> 2, b = img & 3;
    int y, x;
    if (rp < 66) { y = 0; x = rp; }
    else if (rp < 132) { y = 65; x = rp - 66; }
    else { int s2 = rp - 132; y = 1 + (s2 >> 1); x = (s2 & 1) * 65; }
    unsigned short* base = (buf == 0) ? h1h : (buf == 1) ? h2h : xth;
    unsigned* p = (unsigned*)(base + ((size_t)b * HPIX + y * HH + x) * 256);
    p[threadIdx.x] = 0;
}

// ---------------------------------------------------------------- prod
__global__ void k_prod(const float* __restrict__ xn, const float* __restrict__ xr,
                       float* __restrict__ prod) {
    __shared__ float red[4][64];
    int px0 = blockIdx.x * 64;
    int b = px0 >> 12;
    int pxl = threadIdx.x & 63, cg = threadIdx.x >> 6;
    size_t base = (size_t)b * 256 * HWp + (px0 & 4095) + pxl;
    const float* a = xn + base;
    const float* r = xr + base;
    float s = 0.f;
#pragma unroll 8
    for (int c = cg * 64; c < cg * 64 + 64; ++c)
        s += a[(size_t)c * HWp] * r[(size_t)c * HWp];
    red[cg][pxl] = s;
    __syncthreads();
    if (cg == 0)
        prod[px0 + pxl] = red[0][pxl] + red[1][pxl] + red[2][pxl] + red[3][pxl];
}

// ---------------------------------------------------------------- corr
__global__ void k_corr(const float* __restrict__ prod, float* __restrict__ corr) {
    int p = blockIdx.x * blockDim.x + threadIdx.x;
    if (p >= NPIX) return;
    int b = p >> 12, yx = p & 4095, y = yx >> 6, x = yx & 63;
    float s = 0.f;
    for (int dy = -1; dy <= 1; ++dy) {
        int yy = y + dy;
        if (yy < 0 || yy >= Hh) continue;
        for (int dx = -1; dx <= 1; ++dx) {
            int xx = x + dx;
            if (xx < 0 || xx >= Wwd) continue;
            s += prod[b * HWp + yy * Wwd + xx];
        }
    }
    s *= (1.0f / 256.0f);
    corr[p] = (s > 0.f) ? s : 0.1f * s;
}

// ---------------------------------------------------------------- conv1 (Cin=1) -> h1h NHWC halo bf16
__global__ __launch_bounds__(256) void k_conv1(const float* __restrict__ corr,
                                               const float* __restrict__ w1,
                                               const float* __restrict__ b1,
                                               unsigned short* __restrict__ h1h) {
    __shared__ float pt[3][34];
    int px0 = blockIdx.x * 32;
    int b = px0 >> 12, y = (px0 & 4095) >> 6, x0 = px0 & 63;
    int tid = threadIdx.x;
    if (tid < 102) {
        int i = tid / 34, j = tid - i * 34;
        int yy = y - 1 + i, xx = x0 - 1 + j;
        float v = 0.f;
        if (yy >= 0 && yy < Hh && xx >= 0 && xx < Wwd) v = corr[b * HWp + yy * Wwd + xx];
        pt[i][j] = v;
    }
    float wl[9];
#pragma unroll
    for (int k = 0; k < 9; ++k) wl[k] = w1[tid * 9 + k];
    float bias = b1[tid];
    __syncthreads();
    for (int p = 0; p < 32; ++p) {
        float acc = bias;
#pragma unroll
        for (int ky = 0; ky < 3; ++ky)
#pragma unroll
            for (int kx = 0; kx < 3; ++kx) acc = fmaf(pt[ky][p + kx], wl[ky * 3 + kx], acc);
        acc = fmaxf(acc, 0.f);
        h1h[((size_t)b * HPIX + (y + 1) * HH + (x0 + p + 1)) * 256 + tid] = f2bf(acc);
    }
}

// ---------------------------------------------------------------- x_ref NCHW f32 -> NHWC halo bf16
__global__ void k_xth(const float* __restrict__ in, unsigned short* __restrict__ out) {
    __shared__ float t[32][33];
    int b = blockIdx.z;
    int c0 = blockIdx.y * 32;
    int y = blockIdx.x >> 1, x0 = (blockIdx.x & 1) * 32;
    int tx = threadIdx.x, ty = threadIdx.y;
#pragma unroll
    for (int i = 0; i < 32; i += 8)
        t[ty + i][tx] = in[((size_t)b * 256 + c0 + ty + i) * HWp + y * Wwd + x0 + tx];
    __syncthreads();
#pragma unroll
    for (int i = 0; i < 32; i += 8)
        out[((size_t)b * HPIX + (y + 1) * HH + (x0 + ty + i + 1)) * 256 + c0 + tx] =
            f2bf(t[tx][ty + i]);
}

// ---------------------------------------------------------------- weight pack (linear, conv3g)
__global__ void k_pack(const float* __restrict__ w, unsigned short* __restrict__ out, int O_in) {
    int i = blockIdx.x * 256 + threadIdx.x;
    int o = i / Kdim;
    int r = i - o * Kdim;
    int k = r >> 8, c = r & 255;
    float v = (o < O_in) ? w[((size_t)o * 256 + c) * 9 + k] : 0.f;
    out[i] = f2bf(v);
}

// ---------------------------------------------------------------- frag-pack for 8-wave 32o tiles
__global__ void k_packf(const float* __restrict__ w, unsigned short* __restrict__ out) {
    int i = blockIdx.x * 256 + threadIdx.x;          // 589824 total
    int e = i & 7;
    int lane = (i >> 3) & 63;
    int mi = (i >> 9) & 1;
    int kf = (i >> 10) & 1;
    int rest = i >> 11;                               // [0,288)
    int s = rest % 36;
    int wv = rest / 36;
    int o = wv * 32 + mi * 16 + (lane & 15);
    int kk = s * 64 + (kf * 4 + (lane >> 4)) * 8 + e;
    int c = kk & 255, tap = kk >> 8;
    out[i] = f2bf(w[((size_t)o * 256 + c) * 9 + tap]);
}

// ---------------------------------------------------------------- conv2 GEMM: 64px x 256o, 8 waves, 2-deep prefetch
__global__ __launch_bounds__(512) void k_conv2g(const unsigned short* __restrict__ h1h,
                                                const unsigned short* __restrict__ wbf,
                                                const float* __restrict__ bias,
                                                unsigned short* __restrict__ h2h) {
    __shared__ short S_s[2][64 * 64];
    const int tid = threadIdx.x;
    const int bid = blockIdx.x;
    const int px0 = ((bid & 7) * 32 + (bid >> 3)) * 64;   // XCD-bijective
    const int b = px0 >> 12;
    const unsigned short* hb = h1h + (size_t)b * HPIX * 256;
    const int pxl = tid >> 3;
    const int px = px0 + pxl;
    const int y = (px & 4095) >> 6, x = px & 63;
    const int u0 = tid & 7;
    const int lane = tid & 63, wv = tid >> 6;
    const unsigned short* wfb = wbf + (size_t)wv * NSTEP * 2048 + lane * 8;
    const unsigned short* abase0 = hb + (size_t)((y + 1) * HH + (x + 1)) * 256 + u0 * 8;

    f32x4 acc[4][2] = {};
    u32x4 wA[4], wB[4], aA, aB;
    float bia[2];
#pragma unroll
    for (int oi = 0; oi < 2; ++oi) bia[oi] = bias[wv * 32 + oi * 16 + (lane & 15)];

    const int wr0 = pxl * 64 + ((u0 ^ (pxl & 7)) << 3);

    auto WLOAD = [&](int s, u32x4 (&wreg)[4]) {
#pragma unroll
        for (int f = 0; f < 4; ++f)
            wreg[f] = *(const u32x4*)(wfb + ((size_t)s * 4 + f) * 512);
    };
    auto ALOAD = [&](int s) {
        int tap = s >> 2, chunk = s & 3;
        int aoff = ((tap / 3 - 1) * HH + (tap % 3 - 1)) * 256 + chunk * 64;
        return *(const u32x4*)(abase0 + aoff);
    };

    // prologue: step0 staged, step1 data in flight
    {
        u32x4 a0 = ALOAD(0);
        WLOAD(0, wA);
        *(u32x4*)&S_s[0][wr0] = a0;
        aA = ALOAD(1);
        asm volatile("s_waitcnt lgkmcnt(0)" ::: "memory");
    }

    auto ITER = [&](int s, u32x4 (&wcur)[4], u32x4 (&wnxt)[4], u32x4& aCur, u32x4& aNxt,
                    short* SBc, short* SBn) {
        __builtin_amdgcn_s_barrier();
        __builtin_amdgcn_sched_barrier(0);
        if (s + 1 < NSTEP) *(u32x4*)&SBn[wr0] = aCur;      // stage step s+1 (data 1 iter old)
        if (s + 2 < NSTEP) aNxt = ALOAD(s + 2);            // issue 2 ahead
        if (s + 1 < NSTEP) WLOAD(s + 1, wnxt);
        short8v af[4][2];
#pragma unroll
        for (int pi = 0; pi < 4; ++pi) {
            int row = pi * 16 + (lane & 15);
#pragma unroll
            for (int kf = 0; kf < 2; ++kf) {
                int c8 = kf * 4 + (lane >> 4);
                af[pi][kf] = *(const short8v*)&SBc[row * 64 + ((c8 ^ (row & 7)) << 3)];
            }
        }
        __builtin_amdgcn_s_setprio(1);
#pragma unroll
        for (int kf = 0; kf < 2; ++kf)
#pragma unroll
            for (int pi = 0; pi < 4; ++pi)
#pragma unroll
                for (int oi = 0; oi < 2; ++oi)
                    acc[pi][oi] = __builtin_amdgcn_mfma_f32_16x16x32_bf16(
                        af[pi][kf], __builtin_bit_cast(short8v, wcur[kf * 2 + oi]),
                        acc[pi][oi], 0, 0, 0);
        __builtin_amdgcn_s_setprio(0);
        asm volatile("s_waitcnt lgkmcnt(0)" ::: "memory");
    };

    for (int s2 = 0; s2 < NSTEP; s2 += 2) {
        ITER(s2, wA, wB, aA, aB, &S_s[0][0], &S_s[1][0]);
        ITER(s2 + 1, wB, wA, aB, aA, &S_s[1][0], &S_s[0][0]);
    }

#pragma unroll
    for (int pi = 0; pi < 4; ++pi) {
#pragma unroll
        for (int j = 0; j < 4; ++j) {
            int p2 = px0 + pi * 16 + (lane >> 4) * 4 + j;
            int yy = (p2 & 4095) >> 6, xx = p2 & 63;
            unsigned short* dst = h2h + ((size_t)b * HPIX + (yy + 1) * HH + (xx + 1)) * 256;
#pragma unroll
            for (int oi = 0; oi < 2; ++oi) {
                int o = wv * 32 + oi * 16 + (lane & 15);
                dst[o] = f2bf(fmaxf(acc[pi][oi][j] + bia[oi], 0.f));
            }
        }
    }
}

// ---------------------------------------------------------------- conv3 GEMM: 64px x 32o, BK=64, dbuf (unchanged)
__global__ __launch_bounds__(256) void k_conv3g(const unsigned short* __restrict__ h2h,
                                                const unsigned short* __restrict__ wb,
                                                const float* __restrict__ bias,
                                                float* __restrict__ offp) {
    __shared__ short A_s[2][64 * 64];
    __shared__ short B_s[2][32 * 64];
    const int tid = threadIdx.x;
    const int px0 = blockIdx.x * 64;
    const int b = px0 >> 12;
    const unsigned short* hb = h2h + (size_t)b * HPIX * 256;

    const unsigned short* abase[2];
#pragma unroll
    for (int i = 0; i < 2; ++i) {
        int u = i * 256 + tid;
        int pxl = u >> 3;
        int pxg = px0 + pxl;
        int y = (pxg & 4095) >> 6, x = pxg & 63;
        abase[i] = hb + (size_t)((y + 1) * HH + (x + 1)) * 256 + swz(u);
    }
    const unsigned short* bbase = wb + (size_t)(tid >> 3) * Kdim + swz(tid);

    const int lane = tid & 63, wv = tid >> 6;
    f32x4 acc[2] = {};

    auto STAGE = [&](int s, int buf) {
        int tap = s >> 2, chunk = s & 3;
        int delta = ((tap / 3 - 1) * HH + (tap % 3 - 1)) * 256 + chunk * 64;
        short* Ab = &A_s[buf][0];
#pragma unroll
        for (int i = 0; i < 2; ++i) gload_lds16(abase[i] + delta, Ab + (i * 256 + tid) * 8);
        gload_lds16(bbase + s * 64, &B_s[buf][tid * 8]);
    };

    STAGE(0, 0);
    __syncthreads();
    for (int s = 0; s < NSTEP; ++s) {
        int cur = s & 1;
        if (s + 1 < NSTEP) STAGE(s + 1, cur ^ 1);
        const short* Ab = &A_s[cur][0];
        const short* Bb = &B_s[cur][0];
        short8v af[2], bf[2][2];
#pragma unroll
        for (int kf = 0; kf < 2; ++kf) {
            int row = wv * 16 + (lane & 15);
            int c8 = kf * 4 + (lane >> 4);
            af[kf] = *(const short8v*)&Ab[row * 64 + ((c8 ^ (row & 7)) << 3)];
        }
#pragma unroll
        for (int ni = 0; ni < 2; ++ni) {
            int row = ni * 16 + (lane & 15);
#pragma unroll
            for (int kf = 0; kf < 2; ++kf) {
                int c8 = kf * 4 + (lane >> 4);
                bf[ni][kf] = *(const short8v*)&Bb[row * 64 + ((c8 ^ (row & 7)) << 3)];
            }
        }
#pragma unroll
        for (int kf = 0; kf < 2; ++kf)
#pragma unroll
            for (int ni = 0; ni < 2; ++ni)
                acc[ni] = __builtin_amdgcn_mfma_f32_16x16x32_bf16(af[kf], bf[ni][kf], acc[ni], 0, 0, 0);
        __syncthreads();
    }
#pragma unroll
    for (int j = 0; j < 4; ++j) {
        int px = px0 + wv * 16 + (lane >> 4) * 4 + j;
#pragma unroll
        for (int ni = 0; ni < 2; ++ni) {
            int o = ni * 16 + (lane & 15);
            float bv = (o < 18) ? bias[o] : 0.f;
            offp[(size_t)px * 32 + o] = fmaxf(acc[ni][j] + bv, 0.f);
        }
    }
}

// ---------------------------------------------------------------- dcn GEMM: 64px x 256o, 8 waves, 2-deep gather prefetch
__global__ __launch_bounds__(512) void k_dcng(const unsigned short* __restrict__ xth,
                                              const float* __restrict__ offp,
                                              const unsigned short* __restrict__ wbf,
                                              const float* __restrict__ xn,
                                              float* __restrict__ out) {
    __shared__ short S_s[2][64 * 64];
    const int tid = threadIdx.x;
    const int bid = blockIdx.x;
    const int px0 = ((bid & 7) * 32 + (bid >> 3)) * 64;   // XCD-bijective
    const int b = px0 >> 12;
    const unsigned short* xb = xth + (size_t)b * HPIX * 256;
    const int pxl = tid >> 3;
    const int px = px0 + pxl;
    const int y = (px & 4095) >> 6, x = px & 63;
    const int u0 = tid & 7;
    const int lane = tid & 63, wv = tid >> 6;
    const unsigned short* wfb = wbf + (size_t)wv * NSTEP * 2048 + lane * 8;
    const float2* offv = (const float2*)offp;

    f32x4 acc[2][4] = {};
    u32x4 wA[4], wB[4];
    u32x4 gA[4], gB[4];                                // 2-deep gather ping-pong
    const int wr0 = pxl * 64 + ((u0 ^ (pxl & 7)) << 3);

    const unsigned short* pcorner[4];
    f32x2 wpair[4];
    float2 offn;

    auto SETUP = [&](int tap, float dyo, float dxo) {
        int ky = tap / 3 - 1, kx = tap % 3 - 1;
        float ypos = (float)(y + ky) + dyo;
        float xpos = (float)(x + kx) + dxo;
        float y0f = floorf(ypos), x0f = floorf(xpos);
        float wy = ypos - y0f, wx = xpos - x0f;
        int y0 = (int)y0f, x0 = (int)x0f;
        bool y0v = (y0 >= 0) && (y0 < Hh), y1v = (y0 + 1 >= 0) && (y0 + 1 < Hh);
        bool x0v = (x0 >= 0) && (x0 < Wwd), x1v = (x0 + 1 >= 0) && (x0 + 1 < Wwd);
        int hy0 = min(max(y0, -1), 64) + 1, hy1 = min(max(y0 + 1, -1), 64) + 1;
        int hx0 = min(max(x0, -1), 64) + 1, hx1 = min(max(x0 + 1, -1), 64) + 1;
        float w0 = (1.f - wy) * (1.f - wx) * (float)(y0v && x0v);
        float w1 = (1.f - wy) * wx * (float)(y0v && x1v);
        float w2 = wy * (1.f - wx) * (float)(y1v && x0v);
        float w3 = wy * wx * (float)(y1v && x1v);
        wpair[0] = (f32x2){w0, w0};
        wpair[1] = (f32x2){w1, w1};
        wpair[2] = (f32x2){w2, w2};
        wpair[3] = (f32x2){w3, w3};
        pcorner[0] = xb + (size_t)((hy0 * HH + hx0) * 256) + u0 * 8;
        pcorner[1] = xb + (size_t)((hy0 * HH + hx1) * 256) + u0 * 8;
        pcorner[2] = xb + (size_t)((hy1 * HH + hx0) * 256) + u0 * 8;
        pcorner[3] = xb + (size_t)((hy1 * HH + hx1) * 256) + u0 * 8;
    };
    auto WLOAD = [&](int s, u32x4 (&wreg)[4]) {
#pragma unroll
        for (int f = 0; f < 4; ++f)
            wreg[f] = *(const u32x4*)(wfb + ((size_t)s * 4 + f) * 512);
    };
    auto GISSUE = [&](int s, u32x4 (&g)[4]) {
        const int nco = (s & 3) * 64;
#pragma unroll
        for (int c = 0; c < 4; ++c) g[c] = *(const u32x4*)(pcorner[c] + nco);
    };
    auto COMBINE_WRITE = [&](u32x4 (&g)[4], short* SBn) {
        u32x4 res;
#pragma unroll
        for (int qd = 0; qd < 4; ++qd) {
            f32x2 a = pk_mul(unpack2(g[0][qd]), wpair[0]);
            a = pk_fma(unpack2(g[1][qd]), wpair[1], a);
            a = pk_fma(unpack2(g[2][qd]), wpair[2], a);
            a = pk_fma(unpack2(g[3][qd]), wpair[3], a);
            res[qd] = cvt_pk_bf16(a.x, a.y);
        }
        *(u32x4*)&SBn[wr0] = res;
    };

    // prologue: step0 combined+staged; step1 gathers in flight (gA)
    {
        float2 o0 = offv[(size_t)px * 16];
        SETUP(0, o0.x, o0.y);
        u32x4 g0[4];
        GISSUE(0, g0);
        WLOAD(0, wA);
        COMBINE_WRITE(g0, &S_s[0][0]);
        GISSUE(1, gA);
        asm volatile("s_waitcnt lgkmcnt(0)" ::: "memory");
    }

    auto ITER = [&](int s, u32x4 (&wcur)[4], u32x4 (&wnxt)[4],
                    u32x4 (&gcur)[4], u32x4 (&gnxt)[4], short* SBc, short* SBn) {
        __builtin_amdgcn_s_barrier();
        __builtin_amdgcn_sched_barrier(0);
        // stage step s+1 from gathers issued 1 iteration ago (uses current-tap wpair)
        if (s + 1 < NSTEP) COMBINE_WRITE(gcur, SBn);
        // tap-context management for 2-ahead issue
        if ((s & 3) == 0 && (s >> 2) + 1 < 9)
            offn = offv[(size_t)px * 16 + (s >> 2) + 1];
        if ((s & 3) == 2 && s + 2 < NSTEP)
            SETUP((s + 2) >> 2, offn.x, offn.y);       // safe: combine for s+1 already done
        if (s + 2 < NSTEP) GISSUE(s + 2, gnxt);        // 2 steps ahead
        if (s + 1 < NSTEP) WLOAD(s + 1, wnxt);
        short8v sf[4][2];
#pragma unroll
        for (int ni = 0; ni < 4; ++ni) {
            int row = ni * 16 + (lane & 15);
#pragma unroll
            for (int kf = 0; kf < 2; ++kf) {
                int c8 = kf * 4 + (lane >> 4);
                sf[ni][kf] = *(const short8v*)&SBc[row * 64 + ((c8 ^ (row & 7)) << 3)];
            }
        }
        __builtin_amdgcn_s_setprio(1);
#pragma unroll
        for (int kf = 0; kf < 2; ++kf)
#pragma unroll
            for (int mi = 0; mi < 2; ++mi)
#pragma unroll
                for (int ni = 0; ni < 4; ++ni)
                    acc[mi][ni] = __builtin_amdgcn_mfma_f32_16x16x32_bf16(
                        __builtin_bit_cast(short8v, wcur[kf * 2 + mi]), sf[ni][kf],
                        acc[mi][ni], 0, 0, 0);
        __builtin_amdgcn_s_setprio(0);
        asm volatile("s_waitcnt lgkmcnt(0)" ::: "memory");
    };

    for (int s2 = 0; s2 < NSTEP; s2 += 2) {
        ITER(s2, wA, wB, gA, gB, &S_s[0][0], &S_s[1][0]);
        ITER(s2 + 1, wB, wA, gB, gA, &S_s[1][0], &S_s[0][0]);
    }

#pragma unroll
    for (int mi = 0; mi < 2; ++mi) {
        int o = wv * 32 + mi * 16 + (lane >> 4) * 4;
#pragma unroll
        for (int j = 0; j < 4; ++j) {
            size_t rowbase = ((size_t)b * 256 + o + j) * HWp;
#pragma unroll
            for (int ni = 0; ni < 4; ++ni) {
                int p2 = (px0 + ni * 16 + (lane & 15)) & 4095;
                size_t idx = rowbase + p2;
                out[idx] = 0.5f * (xn[idx] + fmaxf(acc[mi][ni][j], 0.f));
            }
        }
    }
}

extern "C" void kernel_launch(void* const* d_in, const int* in_sizes, int n_in,
                              void* d_out, int out_size, void* d_ws, size_t ws_size,
                              hipStream_t stream) {
    const float* x_ref  = (const float*)d_in[0];
    const float* x_next = (const float*)d_in[1];
    const float* w1 = (const float*)d_in[2];
    const float* b1 = (const float*)d_in[3];
    const float* w2 = (const float*)d_in[4];
    const float* b2 = (const float*)d_in[5];
    const float* w3 = (const float*)d_in[6];
    const float* b3 = (const float*)d_in[7];
    const float* wd = (const float*)d_in[8];
    float* out = (float*)d_out;
    char* ws = (char*)d_ws;

    unsigned short* h1h = (unsigned short*)(ws + B_H1H);
    unsigned short* h2h = (unsigned short*)(ws + B_H2H);
    unsigned short* xth = (unsigned short*)(ws + B_XTH);
    float* prod = (float*)(ws + B_PROD);
    float* corr = (float*)(ws + B_CORR);
    float* offp = (float*)(ws + B_OFFP);
    unsigned short* wb2f = (unsigned short*)(ws + B_WB2);
    unsigned short* wbdf = (unsigned short*)(ws + B_WBD);
    unsigned short* wb3  = (unsigned short*)(ws + B_WB3);

    k_zero_ring<<<12 * 260, 128, 0, stream>>>(h1h, h2h, xth);
    k_prod<<<NPIX / 64, 256, 0, stream>>>(x_next, x_ref, prod);
    k_corr<<<NPIX / 256, 256, 0, stream>>>(prod, corr);
    k_conv1<<<NPIX / 32, 256, 0, stream>>>(corr, w1, b1, h1h);
    k_xth<<<dim3(128, 8, Bsz), dim3(32, 8), 0, stream>>>(x_ref, xth);
    k_packf<<<(256 * Kdim) / 256, 256, 0, stream>>>(w2, wb2f);
    k_packf<<<(256 * Kdim) / 256, 256, 0, stream>>>(wd, wbdf);
    k_pack<<<(32 * Kdim) / 256, 256, 0, stream>>>(w3, wb3, 18);
    k_conv2g<<<256, 512, 0, stream>>>(h1h, wb2f, b2, h2h);
    k_conv3g<<<256, 256, 0, stream>>>(h2h, wb3, b3, offp);
    k_dcng<<<256, 512, 0, stream>>>(xth, offp, wbdf, x_next, out);
}